// Round 1
// baseline (1115.540 us; speedup 1.0000x reference)
//
#include <hip/hip_runtime.h>
#include <math.h>

#define N_   64
#define C_   512
#define HW_  256
#define M_   2000
#define KCLS 10

// ---------------------------------------------------------------------------
// gather: memT[k][c][m] = memory[(c*M_+m)*KCLS + k]   (make m contiguous)
// ---------------------------------------------------------------------------
__global__ __launch_bounds__(256) void gather_mem(const float* __restrict__ mem,
                                                  float* __restrict__ memT) {
    int idx = blockIdx.x * 256 + threadIdx.x;   // over c*M_
    if (idx >= C_ * M_) return;
#pragma unroll
    for (int k = 0; k < KCLS; ++k)
        memT[k * (C_ * M_) + idx] = mem[idx * KCLS + k];
}

// ---------------------------------------------------------------------------
// m2[k][m] = sum_c memT[k][c][m]^2
// ---------------------------------------------------------------------------
__global__ __launch_bounds__(256) void m2_kernel(const float* __restrict__ memT,
                                                 float* __restrict__ m2) {
    int m = blockIdx.x * 256 + threadIdx.x;
    int k = blockIdx.y;
    if (m >= M_) return;
    const float* B = memT + k * (C_ * M_);
    float s = 0.f;
    for (int c = 0; c < C_; ++c) {
        float v = B[c * M_ + m];
        s += v * v;
    }
    m2[k * M_ + m] = s;
}

// ---------------------------------------------------------------------------
// sim[n][p][m] = 2 * sum_c z[n][c][p] * memT[cls[n]][c][m]  -  m2[cls[n]][m]
// (z2 term dropped: constant along softmax axis, cancels exactly)
// Tile: 64p x 64m, BK=16, 256 threads, 4x4 microtile.
// ---------------------------------------------------------------------------
__global__ __launch_bounds__(256) void sim_gemm(const float* __restrict__ z,
                                                const int* __restrict__ cls,
                                                const float* __restrict__ memT,
                                                const float* __restrict__ m2,
                                                float* __restrict__ simbuf) {
    const int mt = blockIdx.x;     // 0..31
    const int pt = blockIdx.y;     // 0..3
    const int n  = blockIdx.z;     // 0..63
    const int kc = cls[n];
    const int m0 = mt * 64, p0 = pt * 64;
    const float* A = z + n * (C_ * HW_);        // [c][p], p contiguous
    const float* B = memT + kc * (C_ * M_);     // [c][m], m contiguous

    __shared__ float As[16][64];
    __shared__ float Bs[16][64];

    const int tid = threadIdx.x;
    const int tx = tid & 15, ty = tid >> 4;
    const int pp = tid & 63, kb = tid >> 6;     // loader mapping

    float acc[4][4] = {};

    for (int k0 = 0; k0 < C_; k0 += 16) {
#pragma unroll
        for (int i = 0; i < 4; ++i) {
            int kk = kb + i * 4;
            As[kk][pp] = A[(k0 + kk) * HW_ + p0 + pp];
            int mm = m0 + pp;
            Bs[kk][pp] = (mm < M_) ? B[(k0 + kk) * M_ + mm] : 0.f;
        }
        __syncthreads();
#pragma unroll
        for (int kk = 0; kk < 16; ++kk) {
            float4 a = *reinterpret_cast<const float4*>(&As[kk][ty * 4]);
            float4 b = *reinterpret_cast<const float4*>(&Bs[kk][tx * 4]);
            float av[4] = {a.x, a.y, a.z, a.w};
            float bv[4] = {b.x, b.y, b.z, b.w};
#pragma unroll
            for (int i = 0; i < 4; ++i)
#pragma unroll
                for (int j = 0; j < 4; ++j)
                    acc[i][j] = fmaf(av[i], bv[j], acc[i][j]);
        }
        __syncthreads();
    }

#pragma unroll
    for (int i = 0; i < 4; ++i) {
        int p = p0 + ty * 4 + i;
        int base = (n * HW_ + p) * M_;
#pragma unroll
        for (int j = 0; j < 4; ++j) {
            int m = m0 + tx * 4 + j;
            if (m < M_) simbuf[base + m] = 2.f * acc[i][j] - m2[kc * M_ + m];
        }
    }
}

// ---------------------------------------------------------------------------
// Row softmax over m=2000. One block per (n,p) row.
// Reads sim from simbuf (== log_w slot), writes w_hat (opt), w, log_w.
// ---------------------------------------------------------------------------
__global__ __launch_bounds__(256) void softmax_kernel(const float* __restrict__ simbuf,
                                                      float* __restrict__ w_hat,
                                                      float* __restrict__ w,
                                                      float* __restrict__ logw,
                                                      int write_hat) {
    const int r = blockIdx.x;                 // 0..16383
    const float* srow = simbuf + (size_t)r * M_;
    const int t = threadIdx.x;

    float s0[8];
    float lmax = -INFINITY;
#pragma unroll
    for (int i = 0; i < 8; ++i) {
        int idx = t + i * 256;
        float x = (idx < M_) ? srow[idx] : -INFINITY;
        s0[i] = x;
        lmax = fmaxf(lmax, x);
    }
#pragma unroll
    for (int off = 32; off >= 1; off >>= 1)
        lmax = fmaxf(lmax, __shfl_xor(lmax, off));

    __shared__ float wred[4];
    __shared__ float wsum[4];
    const int wid = t >> 6, lane = t & 63;
    if (lane == 0) wred[wid] = lmax;
    __syncthreads();
    const float gmax = fmaxf(fmaxf(wred[0], wred[1]), fmaxf(wred[2], wred[3]));

    float e[8];
    float lsum = 0.f;
#pragma unroll
    for (int i = 0; i < 8; ++i) {
        int idx = t + i * 256;
        if (idx < M_) {
            e[i] = __expf(s0[i] - gmax);
            lsum += e[i];
        }
    }
#pragma unroll
    for (int off = 32; off >= 1; off >>= 1)
        lsum += __shfl_xor(lsum, off);
    if (lane == 0) wsum[wid] = lsum;
    __syncthreads();
    const float gsum = wsum[0] + wsum[1] + wsum[2] + wsum[3];
    const float inv = 1.f / gsum;
    const float lg  = __logf(gsum);

    size_t base = (size_t)r * M_;
#pragma unroll
    for (int i = 0; i < 8; ++i) {
        int idx = t + i * 256;
        if (idx < M_) {
            float wv = e[i] * inv;
            w[base + idx] = wv;
            if (write_hat) w_hat[base + idx] = wv;
            logw[base + idx] = (s0[i] - gmax) - lg;
        }
    }
}

// ---------------------------------------------------------------------------
// z_hat[n][c][p] = sum_m memT[cls[n]][c][m] * w[n][p][m]
// Tile: 64c x 64p, BK=16 (over m), both operands K-major.
// ---------------------------------------------------------------------------
__global__ __launch_bounds__(256) void zhat_gemm(const float* __restrict__ memT,
                                                 const int* __restrict__ cls,
                                                 const float* __restrict__ w,
                                                 float* __restrict__ zhat) {
    const int pt = blockIdx.x;    // 0..3
    const int ct = blockIdx.y;    // 0..7
    const int n  = blockIdx.z;    // 0..63
    const int kc = cls[n];
    const int c0 = ct * 64, p0 = pt * 64;
    const float* A = memT + kc * (C_ * M_);     // [c][m]
    const float* B = w + n * (HW_ * M_);        // [p][m]

    __shared__ float As[16][68];   // pad 68: 16B-aligned rows, conflict-free
    __shared__ float Bs[16][68];

    const int tid = threadIdx.x;
    const int tx = tid & 15, ty = tid >> 4;
    const int cc = tid >> 2, kb = (tid & 3) * 4;   // loader mapping

    float acc[4][4] = {};

    for (int m0 = 0; m0 < M_; m0 += 16) {
        float4 av = *reinterpret_cast<const float4*>(&A[(c0 + cc) * M_ + m0 + kb]);
        float4 bv = *reinterpret_cast<const float4*>(&B[(p0 + cc) * M_ + m0 + kb]);
        As[kb + 0][cc] = av.x; As[kb + 1][cc] = av.y;
        As[kb + 2][cc] = av.z; As[kb + 3][cc] = av.w;
        Bs[kb + 0][cc] = bv.x; Bs[kb + 1][cc] = bv.y;
        Bs[kb + 2][cc] = bv.z; Bs[kb + 3][cc] = bv.w;
        __syncthreads();
#pragma unroll
        for (int kk = 0; kk < 16; ++kk) {
            float4 a = *reinterpret_cast<const float4*>(&As[kk][ty * 4]);
            float4 b = *reinterpret_cast<const float4*>(&Bs[kk][tx * 4]);
            float av4[4] = {a.x, a.y, a.z, a.w};
            float bv4[4] = {b.x, b.y, b.z, b.w};
#pragma unroll
            for (int i = 0; i < 4; ++i)
#pragma unroll
                for (int j = 0; j < 4; ++j)
                    acc[i][j] = fmaf(av4[i], bv4[j], acc[i][j]);
        }
        __syncthreads();
    }

#pragma unroll
    for (int i = 0; i < 4; ++i) {
        int c = c0 + ty * 4 + i;
        float4 o = make_float4(acc[i][0], acc[i][1], acc[i][2], acc[i][3]);
        *reinterpret_cast<float4*>(&zhat[(n * C_ + c) * HW_ + p0 + tx * 4]) = o;
    }
}

__global__ __launch_bounds__(256) void copy_kernel(const float* __restrict__ src,
                                                   float* __restrict__ dst, int n4) {
    int i = blockIdx.x * 256 + threadIdx.x;
    int stride = gridDim.x * 256;
    for (; i < n4; i += stride)
        reinterpret_cast<float4*>(dst)[i] = reinterpret_cast<const float4*>(src)[i];
}

// ---------------------------------------------------------------------------
extern "C" void kernel_launch(void* const* d_in, const int* in_sizes, int n_in,
                              void* d_out, int out_size, void* d_ws, size_t ws_size,
                              hipStream_t stream) {
    const float* z      = (const float*)d_in[0];
    const int*   cls    = (const int*)d_in[1];
    const float* memory = (const float*)d_in[2];

    float* out   = (float*)d_out;
    float* z_hat = out;                                  //  8,388,608
    float* w_hat = z_hat + (size_t)N_ * C_ * HW_;        // 32,768,000
    float* w     = w_hat + (size_t)N_ * HW_ * M_;        // 32,768,000
    float* logw  = w     + (size_t)N_ * HW_ * M_;        // 32,768,000

    const size_t memT_elems = (size_t)KCLS * C_ * M_;    // 10,240,000
    const size_t need = (memT_elems + (size_t)KCLS * M_) * sizeof(float);

    float* memT;
    float* m2;
    int write_hat;
    if (ws_size >= need) {
        memT = (float*)d_ws;
        m2   = memT + memT_elems;
        write_hat = 1;
    } else {
        // fallback: stage memT+m2 in the w_hat slot, copy w->w_hat at the end
        memT = w_hat;
        m2   = w_hat + memT_elems;
        write_hat = 0;
    }
    float* simbuf = logw;   // stage sim in the log_w slot

    gather_mem<<<(C_ * M_ + 255) / 256, 256, 0, stream>>>(memory, memT);
    m2_kernel<<<dim3((M_ + 255) / 256, KCLS), 256, 0, stream>>>(memT, m2);
    sim_gemm<<<dim3((M_ + 63) / 64, HW_ / 64, N_), 256, 0, stream>>>(z, cls, memT, m2, simbuf);
    softmax_kernel<<<N_ * HW_, 256, 0, stream>>>(simbuf, w_hat, w, logw, write_hat);
    zhat_gemm<<<dim3(HW_ / 64, C_ / 64, N_), 256, 0, stream>>>(memT, cls, w, z_hat);
    if (!write_hat)
        copy_kernel<<<2048, 256, 0, stream>>>(w, w_hat, (N_ * HW_ * M_) / 4);
}

// Round 2
// 324.509 us; speedup vs baseline: 3.4376x; 3.4376x over previous
//
#include <hip/hip_runtime.h>
#include <hip/hip_bf16.h>
#include <math.h>

#define N_   64
#define C_   512
#define HW_  256
#define M_   2000
#define KCLS 10
#define MP_  2048   // M padded to multiple of 128 (zeros in pad)

typedef __attribute__((ext_vector_type(8))) short bf16x8;
typedef __attribute__((ext_vector_type(4))) float f32x4;

__device__ __forceinline__ short f2bf(float x) {
    __hip_bfloat16 b = __float2bfloat16(x);
    return *reinterpret_cast<short*>(&b);
}
__device__ __forceinline__ float bf2f(short s) {
    __hip_bfloat16 b = *reinterpret_cast<__hip_bfloat16*>(&s);
    return __bfloat162float(b);
}

// ---------------------------------------------------------------------------
// memory fp32 [(c*M+m)*10+k] -> mcm bf16 [k][C][MP] (m contig)  and
//                               mmc bf16 [k][MP][C] (c contig), pad m>=2000 = 0
// ---------------------------------------------------------------------------
__global__ __launch_bounds__(256) void gather_mem(const float* __restrict__ mem,
                                                  short* __restrict__ mcm,
                                                  short* __restrict__ mmc) {
    const int m0 = blockIdx.x * 32;
    const int c0 = blockIdx.y * 64;
    __shared__ short tile[KCLS][32][66];
    const int t = threadIdx.x;
    const int mm = t & 31;
    const int m = m0 + mm;
    const int cbase = t >> 5;               // 0..7
    for (int ci = 0; ci < 8; ++ci) {
        const int cl = cbase + ci * 8;      // 0..63
        const int c = c0 + cl;
        short v[KCLS];
        if (m < M_) {
            const float* src = mem + ((size_t)c * M_ + m) * KCLS;
#pragma unroll
            for (int k = 0; k < KCLS; ++k) v[k] = f2bf(src[k]);
        } else {
#pragma unroll
            for (int k = 0; k < KCLS; ++k) v[k] = 0;
        }
#pragma unroll
        for (int k = 0; k < KCLS; ++k) {
            mcm[(size_t)k * (C_ * MP_) + (size_t)c * MP_ + m0 + mm] = v[k];
            tile[k][mm][cl] = v[k];
        }
    }
    __syncthreads();
    const int cc = t & 63;
    const int rbase = t >> 6;               // 0..3
    for (int k = 0; k < KCLS; ++k) {
#pragma unroll
        for (int r = 0; r < 8; ++r) {
            const int mm2 = r * 4 + rbase;
            mmc[(size_t)k * (MP_ * C_) + (size_t)(m0 + mm2) * C_ + c0 + cc] = tile[k][mm2][cc];
        }
    }
}

// ---------------------------------------------------------------------------
// z fp32 [n][c][p] -> zTb bf16 [n][p][c] (c contig)
// ---------------------------------------------------------------------------
__global__ __launch_bounds__(256) void transpose_z(const float* __restrict__ z,
                                                   short* __restrict__ zTb) {
    const int c0 = blockIdx.x * 64;
    const int p0 = blockIdx.y * 64;
    const int n = blockIdx.z;
    const float* zp = z + (size_t)n * C_ * HW_;
    __shared__ short tile[64][70];
    const int t = threadIdx.x;
    const int pp = t & 63;
    const int cb = t >> 6;
#pragma unroll
    for (int i = 0; i < 16; ++i) {
        const int cl = i * 4 + cb;
        tile[cl][pp] = f2bf(zp[(size_t)(c0 + cl) * HW_ + p0 + pp]);
    }
    __syncthreads();
    short* dst = zTb + (size_t)n * HW_ * C_;
    const int cc = t & 63;
    const int pb = t >> 6;
#pragma unroll
    for (int i = 0; i < 16; ++i) {
        const int pl = i * 4 + pb;
        dst[(size_t)(p0 + pl) * C_ + c0 + cc] = tile[cc][pl];
    }
}

// ---------------------------------------------------------------------------
// m2[k][m] = sum_c mcm[k][c][m]^2
// ---------------------------------------------------------------------------
__global__ __launch_bounds__(256) void m2_kernel(const short* __restrict__ mcm,
                                                 float* __restrict__ m2) {
    const int m = blockIdx.x * 256 + threadIdx.x;   // 0..2047
    const int k = blockIdx.y;
    if (m >= M_) return;
    const short* B = mcm + (size_t)k * C_ * MP_;
    float s = 0.f;
    for (int c = 0; c < C_; ++c) {
        float v = bf2f(B[(size_t)c * MP_ + m]);
        s = fmaf(v, v, s);
    }
    m2[k * M_ + m] = s;
}

// ---------------------------------------------------------------------------
// Unified NT MFMA GEMM, 128x128 tile, BK=64, 4 waves, m97 structure.
// MODE 0 (sim):  A=zTb[n] (p x 512), B=mmc[kc] (m x 512, gload_lds),
//                D=sim[p][m] (ld 2000), epilogue 2x - m2, mask m<2000
// MODE 1 (zhat): A=mcm[kc] (c x 2048, gload_lds), B=w fp32 [n] (p x 2000,
//                reg-stage + cvt, K-chunk masked), D=zhat[c][p] (ld 256)
// LDS layout [128 rows][8 slots of 16B], slot XOR-swizzled by (row&7):
// gload_lds dest is linear (rule 21) -> pre-swizzle the GLOBAL source chunk.
// ---------------------------------------------------------------------------
template<int MODE>
__global__ __launch_bounds__(256) void gemm_nt(const short* __restrict__ Ab,
                                               const short* __restrict__ Bb,
                                               const float* __restrict__ Bf,
                                               const int* __restrict__ cls,
                                               const float* __restrict__ m2,
                                               float* __restrict__ Db) {
    constexpr int K  = (MODE == 0) ? C_ : MP_;
    constexpr int SA = (MODE == 0) ? C_ : MP_;   // A row stride (elements)
    const int bx = blockIdx.x, by = blockIdx.y, n = blockIdx.z;
    const int kc = cls[n];
    const int rowA0 = by * 128, colB0 = bx * 128;

    const short* A;
    const short* B  = nullptr;
    const float* BF = nullptr;
    float* D;
    if constexpr (MODE == 0) {
        A = Ab + (size_t)n * HW_ * C_;
        B = Bb + (size_t)kc * MP_ * C_;
        D = Db + (size_t)n * HW_ * M_;
    } else {
        A = Ab + (size_t)kc * C_ * MP_;
        BF = Bf + (size_t)n * HW_ * M_;
        D = Db + (size_t)n * C_ * HW_;
    }

    __shared__ short As[128 * 64];
    __shared__ short Bs[128 * 64];

    const int tid = threadIdx.x;
    const int w = tid >> 6, lane = tid & 63;
    const int wr = w >> 1, wc = w & 1;
    const int srow = lane >> 3, sslot = lane & 7;

    f32x4 acc[4][4];
#pragma unroll
    for (int i = 0; i < 4; ++i)
#pragma unroll
        for (int j = 0; j < 4; ++j) acc[i][j] = (f32x4){0.f, 0.f, 0.f, 0.f};

    for (int k0 = 0; k0 < K; k0 += 64) {
        // ---- stage A: 4 x global_load_lds(16B) per wave, pre-swizzled src ----
#pragma unroll
        for (int i = 0; i < 4; ++i) {
            const int row = w * 32 + i * 8 + srow;
            const int chunk = sslot ^ (row & 7);
            const short* src = A + (size_t)(rowA0 + row) * SA + k0 + chunk * 8;
            __builtin_amdgcn_global_load_lds(
                (const __attribute__((address_space(1))) void*)src,
                (__attribute__((address_space(3))) void*)&As[(w * 32 + i * 8) * 64],
                16, 0, 0);
        }
        // ---- stage B ----
        if constexpr (MODE == 0) {
#pragma unroll
            for (int i = 0; i < 4; ++i) {
                const int row = w * 32 + i * 8 + srow;
                const int chunk = sslot ^ (row & 7);
                const short* src = B + (size_t)(colB0 + row) * C_ + k0 + chunk * 8;
                __builtin_amdgcn_global_load_lds(
                    (const __attribute__((address_space(1))) void*)src,
                    (__attribute__((address_space(3))) void*)&Bs[(w * 32 + i * 8) * 64],
                    16, 0, 0);
            }
        } else {
#pragma unroll
            for (int i = 0; i < 4; ++i) {
                const int row = w * 32 + i * 8 + srow;
                const int kg = k0 + sslot * 8;
                float4 v0 = {0.f, 0.f, 0.f, 0.f}, v1 = {0.f, 0.f, 0.f, 0.f};
                if (kg < M_) {   // 2000 % 8 == 0: chunk is all-or-nothing
                    const float* s = BF + (size_t)(colB0 + row) * M_ + kg;
                    v0 = *reinterpret_cast<const float4*>(s);
                    v1 = *reinterpret_cast<const float4*>(s + 4);
                }
                bf16x8 bv;
                bv[0] = f2bf(v0.x); bv[1] = f2bf(v0.y); bv[2] = f2bf(v0.z); bv[3] = f2bf(v0.w);
                bv[4] = f2bf(v1.x); bv[5] = f2bf(v1.y); bv[6] = f2bf(v1.z); bv[7] = f2bf(v1.w);
                *reinterpret_cast<bf16x8*>(&Bs[row * 64 + (sslot ^ (row & 7)) * 8]) = bv;
            }
        }
        __syncthreads();
        // ---- compute: 16 ds_read_b128 + 32 MFMA per wave ----
        bf16x8 a[4][2], b[4][2];
#pragma unroll
        for (int i = 0; i < 4; ++i)
#pragma unroll
            for (int kk = 0; kk < 2; ++kk) {
                const int ra = wr * 64 + i * 16 + (lane & 15);
                const int slot = kk * 4 + (lane >> 4);
                a[i][kk] = *reinterpret_cast<const bf16x8*>(&As[ra * 64 + (slot ^ (ra & 7)) * 8]);
                const int rb = wc * 64 + i * 16 + (lane & 15);
                b[i][kk] = *reinterpret_cast<const bf16x8*>(&Bs[rb * 64 + (slot ^ (rb & 7)) * 8]);
            }
#pragma unroll
        for (int i = 0; i < 4; ++i)
#pragma unroll
            for (int j = 0; j < 4; ++j)
#pragma unroll
                for (int kk = 0; kk < 2; ++kk)
                    acc[i][j] = __builtin_amdgcn_mfma_f32_16x16x32_bf16(a[i][kk], b[j][kk], acc[i][j], 0, 0, 0);
        __syncthreads();
    }

    // ---- store: D row = A-row ((lane>>4)*4+reg), D col = B-row (lane&15) ----
    if constexpr (MODE == 0) {
#pragma unroll
        for (int j = 0; j < 4; ++j) {
            const int col = colB0 + wc * 64 + j * 16 + (lane & 15);
            if (col < M_) {
                const float m2v = m2[kc * M_ + col];
#pragma unroll
                for (int i = 0; i < 4; ++i) {
                    const int row = rowA0 + wr * 64 + i * 16 + (lane >> 4) * 4;
#pragma unroll
                    for (int r = 0; r < 4; ++r)
                        D[(size_t)(row + r) * M_ + col] = 2.f * acc[i][j][r] - m2v;
                }
            }
        }
    } else {
#pragma unroll
        for (int i = 0; i < 4; ++i) {
            const int row = rowA0 + wr * 64 + i * 16 + (lane >> 4) * 4;
#pragma unroll
            for (int j = 0; j < 4; ++j) {
                const int col = colB0 + wc * 64 + j * 16 + (lane & 15);
#pragma unroll
                for (int r = 0; r < 4; ++r)
                    D[(size_t)(row + r) * HW_ + col] = acc[i][j][r];
            }
        }
    }
}

// ---------------------------------------------------------------------------
// Row softmax over m=2000; reads sim from logw slot, writes w_hat/w/logw.
// ---------------------------------------------------------------------------
__global__ __launch_bounds__(256) void softmax_kernel(const float* __restrict__ simbuf,
                                                      float* __restrict__ w_hat,
                                                      float* __restrict__ w,
                                                      float* __restrict__ logw,
                                                      int write_hat) {
    const int r = blockIdx.x;
    const float* srow = simbuf + (size_t)r * M_;
    const int t = threadIdx.x;

    float s0[8];
    float lmax = -INFINITY;
#pragma unroll
    for (int i = 0; i < 8; ++i) {
        int idx = t + i * 256;
        float x = (idx < M_) ? srow[idx] : -INFINITY;
        s0[i] = x;
        lmax = fmaxf(lmax, x);
    }
#pragma unroll
    for (int off = 32; off >= 1; off >>= 1)
        lmax = fmaxf(lmax, __shfl_xor(lmax, off));

    __shared__ float wred[4];
    __shared__ float wsum[4];
    const int wid = t >> 6, lane = t & 63;
    if (lane == 0) wred[wid] = lmax;
    __syncthreads();
    const float gmax = fmaxf(fmaxf(wred[0], wred[1]), fmaxf(wred[2], wred[3]));

    float e[8];
    float lsum = 0.f;
#pragma unroll
    for (int i = 0; i < 8; ++i) {
        int idx = t + i * 256;
        if (idx < M_) {
            e[i] = __expf(s0[i] - gmax);
            lsum += e[i];
        }
    }
#pragma unroll
    for (int off = 32; off >= 1; off >>= 1)
        lsum += __shfl_xor(lsum, off);
    if (lane == 0) wsum[wid] = lsum;
    __syncthreads();
    const float gsum = wsum[0] + wsum[1] + wsum[2] + wsum[3];
    const float inv = 1.f / gsum;
    const float lg  = __logf(gsum);

    size_t base = (size_t)r * M_;
#pragma unroll
    for (int i = 0; i < 8; ++i) {
        int idx = t + i * 256;
        if (idx < M_) {
            float wv = e[i] * inv;
            w[base + idx] = wv;
            if (write_hat) w_hat[base + idx] = wv;
            logw[base + idx] = (s0[i] - gmax) - lg;
        }
    }
}

__global__ __launch_bounds__(256) void copy_kernel(const float* __restrict__ src,
                                                   float* __restrict__ dst, int n4) {
    int i = blockIdx.x * 256 + threadIdx.x;
    int stride = gridDim.x * 256;
    for (; i < n4; i += stride)
        reinterpret_cast<float4*>(dst)[i] = reinterpret_cast<const float4*>(src)[i];
}

// ---------------------------------------------------------------------------
extern "C" void kernel_launch(void* const* d_in, const int* in_sizes, int n_in,
                              void* d_out, int out_size, void* d_ws, size_t ws_size,
                              hipStream_t stream) {
    const float* z      = (const float*)d_in[0];
    const int*   cls    = (const int*)d_in[1];
    const float* memory = (const float*)d_in[2];

    float* out   = (float*)d_out;
    float* z_hat = out;                                  //  8,388,608 fp32
    float* w_hat = z_hat + (size_t)N_ * C_ * HW_;        // 32,768,000
    float* w     = w_hat + (size_t)N_ * HW_ * M_;        // 32,768,000
    float* logw  = w     + (size_t)N_ * HW_ * M_;        // 32,768,000

    const size_t mcm_sh = (size_t)KCLS * C_ * MP_;       // bf16 elems
    const size_t mmc_sh = mcm_sh;
    const size_t zTb_sh = (size_t)N_ * HW_ * C_;
    const size_t m2_fl  = (size_t)KCLS * M_;
    const size_t need = (mcm_sh + mmc_sh + zTb_sh) * 2 + m2_fl * 4;

    short *mcm, *mmc, *zTb;
    float* m2;
    int write_hat;
    if (ws_size >= need) {
        char* p = (char*)d_ws;
        mcm = (short*)p;          p += mcm_sh * 2;
        mmc = (short*)p;          p += mmc_sh * 2;
        m2  = (float*)p;          p += m2_fl * 4;
        zTb = (short*)p;
        write_hat = 1;
    } else {
        // fallback: stage mcm+mmc+m2 in the w_hat slot, zTb in z_hat slot,
        // copy w -> w_hat at the end.
        char* p = (char*)w_hat;
        mcm = (short*)p;          p += mcm_sh * 2;
        mmc = (short*)p;          p += mmc_sh * 2;
        m2  = (float*)p;
        zTb = (short*)z_hat;
        write_hat = 0;
    }
    float* simbuf = logw;   // stage sim in the logw slot (softmax rewrites it)

    gather_mem<<<dim3(MP_ / 32, C_ / 64), 256, 0, stream>>>(memory, mcm, mmc);
    transpose_z<<<dim3(C_ / 64, HW_ / 64, N_), 256, 0, stream>>>(z, zTb);
    m2_kernel<<<dim3(MP_ / 256, KCLS), 256, 0, stream>>>(mcm, m2);
    gemm_nt<0><<<dim3(MP_ / 128, HW_ / 128, N_), 256, 0, stream>>>(zTb, mmc, nullptr, cls, m2, simbuf);
    softmax_kernel<<<N_ * HW_, 256, 0, stream>>>(simbuf, w_hat, w, logw, write_hat);
    gemm_nt<1><<<dim3(HW_ / 128, C_ / 128, N_), 256, 0, stream>>>(mcm, nullptr, w, cls, m2, z_hat);
    if (!write_hat)
        copy_kernel<<<2048, 256, 0, stream>>>(w, w_hat, (N_ * HW_ * M_) / 4);
}

// Round 3
// 308.440 us; speedup vs baseline: 3.6167x; 1.0521x over previous
//
#include <hip/hip_runtime.h>
#include <hip/hip_bf16.h>
#include <math.h>

#define N_   64
#define C_   512
#define HW_  256
#define M_   2000
#define KCLS 10
#define MP_  2048   // M padded to multiple of 128 (zeros in pad)

typedef __attribute__((ext_vector_type(8))) short bf16x8;
typedef __attribute__((ext_vector_type(4))) float f32x4;

__device__ __forceinline__ short f2bf(float x) {
    __hip_bfloat16 b = __float2bfloat16(x);
    return *reinterpret_cast<short*>(&b);
}
__device__ __forceinline__ float bf2f(short s) {
    __hip_bfloat16 b = *reinterpret_cast<__hip_bfloat16*>(&s);
    return __bfloat162float(b);
}

// ---------------------------------------------------------------------------
// memory fp32 [(c*M+m)*10+k] -> mcm bf16 [k][C][MP] (m contig)  and
//                               mmc bf16 [k][MP][C] (c contig), pad m>=2000 = 0
// ---------------------------------------------------------------------------
__global__ __launch_bounds__(256) void gather_mem(const float* __restrict__ mem,
                                                  short* __restrict__ mcm,
                                                  short* __restrict__ mmc) {
    const int m0 = blockIdx.x * 32;
    const int c0 = blockIdx.y * 64;
    __shared__ short tile[KCLS][32][66];
    const int t = threadIdx.x;
    const int mm = t & 31;
    const int m = m0 + mm;
    const int cbase = t >> 5;               // 0..7
    for (int ci = 0; ci < 8; ++ci) {
        const int cl = cbase + ci * 8;      // 0..63
        const int c = c0 + cl;
        short v[KCLS];
        if (m < M_) {
            const float* src = mem + ((size_t)c * M_ + m) * KCLS;
#pragma unroll
            for (int k = 0; k < KCLS; ++k) v[k] = f2bf(src[k]);
        } else {
#pragma unroll
            for (int k = 0; k < KCLS; ++k) v[k] = 0;
        }
#pragma unroll
        for (int k = 0; k < KCLS; ++k) {
            mcm[(size_t)k * (C_ * MP_) + (size_t)c * MP_ + m0 + mm] = v[k];
            tile[k][mm][cl] = v[k];
        }
    }
    __syncthreads();
    const int cc = t & 63;
    const int rbase = t >> 6;               // 0..3
    for (int k = 0; k < KCLS; ++k) {
#pragma unroll
        for (int r = 0; r < 8; ++r) {
            const int mm2 = r * 4 + rbase;
            mmc[(size_t)k * (MP_ * C_) + (size_t)(m0 + mm2) * C_ + c0 + cc] = tile[k][mm2][cc];
        }
    }
}

// ---------------------------------------------------------------------------
// z fp32 [n][c][p] -> zTb bf16 [n][p][c] (c contig)
// ---------------------------------------------------------------------------
__global__ __launch_bounds__(256) void transpose_z(const float* __restrict__ z,
                                                   short* __restrict__ zTb) {
    const int c0 = blockIdx.x * 64;
    const int p0 = blockIdx.y * 64;
    const int n = blockIdx.z;
    const float* zp = z + (size_t)n * C_ * HW_;
    __shared__ short tile[64][70];
    const int t = threadIdx.x;
    const int pp = t & 63;
    const int cb = t >> 6;
#pragma unroll
    for (int i = 0; i < 16; ++i) {
        const int cl = i * 4 + cb;
        tile[cl][pp] = f2bf(zp[(size_t)(c0 + cl) * HW_ + p0 + pp]);
    }
    __syncthreads();
    short* dst = zTb + (size_t)n * HW_ * C_;
    const int cc = t & 63;
    const int pb = t >> 6;
#pragma unroll
    for (int i = 0; i < 16; ++i) {
        const int pl = i * 4 + pb;
        dst[(size_t)(p0 + pl) * C_ + c0 + cc] = tile[cc][pl];
    }
}

// ---------------------------------------------------------------------------
// m2[k][m] = sum_c mcm[k][c][m]^2
// ---------------------------------------------------------------------------
__global__ __launch_bounds__(256) void m2_kernel(const short* __restrict__ mcm,
                                                 float* __restrict__ m2) {
    const int m = blockIdx.x * 256 + threadIdx.x;   // 0..2047
    const int k = blockIdx.y;
    if (m >= M_) return;
    const short* B = mcm + (size_t)k * C_ * MP_;
    float s = 0.f;
    for (int c = 0; c < C_; ++c) {
        float v = bf2f(B[(size_t)c * MP_ + m]);
        s = fmaf(v, v, s);
    }
    m2[k * M_ + m] = s;
}

// ---------------------------------------------------------------------------
// Unified NT MFMA GEMM, 128x128 tile, BK=64, 4 waves, m97 structure.
// MODE 0 (sim):       A=zTb[n] (p x 512), B=mmc[kc] (m x 512),
//                     D=sim[p][m] (ld 2000), epilogue 2x - m2, mask m<2000
// MODE 1 (zhat fp32): A=mcm[kc] (c x 2048), B=w fp32 (reg-stage+cvt fallback)
// MODE 2 (zhat bf16): A=mcm[kc] (c x 2048), B=wb bf16 [n] (p x 2048),
//                     both via gload_lds; D=zhat[c][p] (ld 256)
// LDS layout [128 rows][8 slots of 16B], slot XOR-swizzled by (row&7):
// gload_lds dest is linear (rule 21) -> pre-swizzle the GLOBAL source chunk.
// ---------------------------------------------------------------------------
template<int MODE>
__global__ __launch_bounds__(256) void gemm_nt(const short* __restrict__ Ab,
                                               const short* __restrict__ Bb,
                                               const float* __restrict__ Bf,
                                               const int* __restrict__ cls,
                                               const float* __restrict__ m2,
                                               float* __restrict__ Db) {
    constexpr int K  = (MODE == 0) ? C_ : MP_;
    constexpr int SA = (MODE == 0) ? C_ : MP_;   // A row stride (elements)
    constexpr int SB = (MODE == 0) ? C_ : MP_;   // B row stride (MODE 0/2)
    const int bx = blockIdx.x, by = blockIdx.y, n = blockIdx.z;
    const int kc = cls[n];
    const int rowA0 = by * 128, colB0 = bx * 128;

    const short* A;
    const short* B  = nullptr;
    const float* BF = nullptr;
    float* D;
    if constexpr (MODE == 0) {
        A = Ab + (size_t)n * HW_ * C_;
        B = Bb + (size_t)kc * MP_ * C_;
        D = Db + (size_t)n * HW_ * M_;
    } else if constexpr (MODE == 1) {
        A = Ab + (size_t)kc * C_ * MP_;
        BF = Bf + (size_t)n * HW_ * M_;
        D = Db + (size_t)n * C_ * HW_;
    } else {
        A = Ab + (size_t)kc * C_ * MP_;
        B = Bb + (size_t)n * HW_ * MP_;
        D = Db + (size_t)n * C_ * HW_;
    }

    __shared__ short As[128 * 64];
    __shared__ short Bs[128 * 64];

    const int tid = threadIdx.x;
    const int w = tid >> 6, lane = tid & 63;
    const int wr = w >> 1, wc = w & 1;
    const int srow = lane >> 3, sslot = lane & 7;

    f32x4 acc[4][4];
#pragma unroll
    for (int i = 0; i < 4; ++i)
#pragma unroll
        for (int j = 0; j < 4; ++j) acc[i][j] = (f32x4){0.f, 0.f, 0.f, 0.f};

    for (int k0 = 0; k0 < K; k0 += 64) {
        // ---- stage A: 4 x global_load_lds(16B) per wave, pre-swizzled src ----
#pragma unroll
        for (int i = 0; i < 4; ++i) {
            const int row = w * 32 + i * 8 + srow;
            const int chunk = sslot ^ (row & 7);
            const short* src = A + (size_t)(rowA0 + row) * SA + k0 + chunk * 8;
            __builtin_amdgcn_global_load_lds(
                (const __attribute__((address_space(1))) void*)src,
                (__attribute__((address_space(3))) void*)&As[(w * 32 + i * 8) * 64],
                16, 0, 0);
        }
        // ---- stage B ----
        if constexpr (MODE != 1) {
#pragma unroll
            for (int i = 0; i < 4; ++i) {
                const int row = w * 32 + i * 8 + srow;
                const int chunk = sslot ^ (row & 7);
                const short* src = B + (size_t)(colB0 + row) * SB + k0 + chunk * 8;
                __builtin_amdgcn_global_load_lds(
                    (const __attribute__((address_space(1))) void*)src,
                    (__attribute__((address_space(3))) void*)&Bs[(w * 32 + i * 8) * 64],
                    16, 0, 0);
            }
        } else {
#pragma unroll
            for (int i = 0; i < 4; ++i) {
                const int row = w * 32 + i * 8 + srow;
                const int kg = k0 + sslot * 8;
                float4 v0 = {0.f, 0.f, 0.f, 0.f}, v1 = {0.f, 0.f, 0.f, 0.f};
                if (kg < M_) {   // 2000 % 8 == 0: chunk is all-or-nothing
                    const float* s = BF + (size_t)(colB0 + row) * M_ + kg;
                    v0 = *reinterpret_cast<const float4*>(s);
                    v1 = *reinterpret_cast<const float4*>(s + 4);
                }
                bf16x8 bv;
                bv[0] = f2bf(v0.x); bv[1] = f2bf(v0.y); bv[2] = f2bf(v0.z); bv[3] = f2bf(v0.w);
                bv[4] = f2bf(v1.x); bv[5] = f2bf(v1.y); bv[6] = f2bf(v1.z); bv[7] = f2bf(v1.w);
                *reinterpret_cast<bf16x8*>(&Bs[row * 64 + (sslot ^ (row & 7)) * 8]) = bv;
            }
        }
        __syncthreads();
        // ---- compute: 16 ds_read_b128 + 32 MFMA per wave ----
        bf16x8 a[4][2], b[4][2];
#pragma unroll
        for (int i = 0; i < 4; ++i)
#pragma unroll
            for (int kk = 0; kk < 2; ++kk) {
                const int ra = wr * 64 + i * 16 + (lane & 15);
                const int slot = kk * 4 + (lane >> 4);
                a[i][kk] = *reinterpret_cast<const bf16x8*>(&As[ra * 64 + (slot ^ (ra & 7)) * 8]);
                const int rb = wc * 64 + i * 16 + (lane & 15);
                b[i][kk] = *reinterpret_cast<const bf16x8*>(&Bs[rb * 64 + (slot ^ (rb & 7)) * 8]);
            }
#pragma unroll
        for (int i = 0; i < 4; ++i)
#pragma unroll
            for (int j = 0; j < 4; ++j)
#pragma unroll
                for (int kk = 0; kk < 2; ++kk)
                    acc[i][j] = __builtin_amdgcn_mfma_f32_16x16x32_bf16(a[i][kk], b[j][kk], acc[i][j], 0, 0, 0);
        __syncthreads();
    }

    // ---- store: D row = A-row ((lane>>4)*4+reg), D col = B-row (lane&15) ----
    if constexpr (MODE == 0) {
#pragma unroll
        for (int j = 0; j < 4; ++j) {
            const int col = colB0 + wc * 64 + j * 16 + (lane & 15);
            if (col < M_) {
                const float m2v = m2[kc * M_ + col];
#pragma unroll
                for (int i = 0; i < 4; ++i) {
                    const int row = rowA0 + wr * 64 + i * 16 + (lane >> 4) * 4;
#pragma unroll
                    for (int r = 0; r < 4; ++r)
                        D[(size_t)(row + r) * M_ + col] = 2.f * acc[i][j][r] - m2v;
                }
            }
        }
    } else {
#pragma unroll
        for (int i = 0; i < 4; ++i) {
            const int row = rowA0 + wr * 64 + i * 16 + (lane >> 4) * 4;
#pragma unroll
            for (int j = 0; j < 4; ++j) {
                const int col = colB0 + wc * 64 + j * 16 + (lane & 15);
#pragma unroll
                for (int r = 0; r < 4; ++r)
                    D[(size_t)(row + r) * HW_ + col] = acc[i][j][r];
            }
        }
    }
}

// ---------------------------------------------------------------------------
// Row softmax over m=2000; reads sim from logw slot, writes w_hat/w/logw and
// (optionally) wb = bf16(w) with zero pad to MP_ for the zhat GEMM B-operand.
// ---------------------------------------------------------------------------
__global__ __launch_bounds__(256) void softmax_kernel(const float* __restrict__ simbuf,
                                                      float* __restrict__ w_hat,
                                                      float* __restrict__ w,
                                                      float* __restrict__ logw,
                                                      short* __restrict__ wb,
                                                      int write_hat) {
    const int r = blockIdx.x;
    const float* srow = simbuf + (size_t)r * M_;
    const int t = threadIdx.x;

    float s0[8];
    float lmax = -INFINITY;
#pragma unroll
    for (int i = 0; i < 8; ++i) {
        int idx = t + i * 256;
        float x = (idx < M_) ? srow[idx] : -INFINITY;
        s0[i] = x;
        lmax = fmaxf(lmax, x);
    }
#pragma unroll
    for (int off = 32; off >= 1; off >>= 1)
        lmax = fmaxf(lmax, __shfl_xor(lmax, off));

    __shared__ float wred[4];
    __shared__ float wsum[4];
    const int wid = t >> 6, lane = t & 63;
    if (lane == 0) wred[wid] = lmax;
    __syncthreads();
    const float gmax = fmaxf(fmaxf(wred[0], wred[1]), fmaxf(wred[2], wred[3]));

    float e[8];
    float lsum = 0.f;
#pragma unroll
    for (int i = 0; i < 8; ++i) {
        int idx = t + i * 256;
        if (idx < M_) {
            e[i] = __expf(s0[i] - gmax);
            lsum += e[i];
        }
    }
#pragma unroll
    for (int off = 32; off >= 1; off >>= 1)
        lsum += __shfl_xor(lsum, off);
    if (lane == 0) wsum[wid] = lsum;
    __syncthreads();
    const float gsum = wsum[0] + wsum[1] + wsum[2] + wsum[3];
    const float inv = 1.f / gsum;
    const float lg  = __logf(gsum);

    size_t base = (size_t)r * M_;
    size_t base2 = (size_t)r * MP_;
#pragma unroll
    for (int i = 0; i < 8; ++i) {
        int idx = t + i * 256;
        if (idx < M_) {
            float wv = e[i] * inv;
            w[base + idx] = wv;
            if (write_hat) w_hat[base + idx] = wv;
            logw[base + idx] = (s0[i] - gmax) - lg;
            if (wb) wb[base2 + idx] = f2bf(wv);
        } else {
            if (wb) wb[base2 + idx] = 0;
        }
    }
}

__global__ __launch_bounds__(256) void copy_kernel(const float* __restrict__ src,
                                                   float* __restrict__ dst, int n4) {
    int i = blockIdx.x * 256 + threadIdx.x;
    int stride = gridDim.x * 256;
    for (; i < n4; i += stride)
        reinterpret_cast<float4*>(dst)[i] = reinterpret_cast<const float4*>(src)[i];
}

// ---------------------------------------------------------------------------
extern "C" void kernel_launch(void* const* d_in, const int* in_sizes, int n_in,
                              void* d_out, int out_size, void* d_ws, size_t ws_size,
                              hipStream_t stream) {
    const float* z      = (const float*)d_in[0];
    const int*   cls    = (const int*)d_in[1];
    const float* memory = (const float*)d_in[2];

    float* out   = (float*)d_out;
    float* z_hat = out;                                  //  8,388,608 fp32
    float* w_hat = z_hat + (size_t)N_ * C_ * HW_;        // 32,768,000
    float* w     = w_hat + (size_t)N_ * HW_ * M_;        // 32,768,000
    float* logw  = w     + (size_t)N_ * HW_ * M_;        // 32,768,000

    const size_t mcm_sh = (size_t)KCLS * C_ * MP_;       // bf16 elems
    const size_t mmc_sh = mcm_sh;
    const size_t zTb_sh = (size_t)N_ * HW_ * C_;
    const size_t wb_sh  = (size_t)N_ * HW_ * MP_;
    const size_t m2_fl  = (size_t)KCLS * M_;
    const size_t need_base = (mcm_sh + mmc_sh + zTb_sh) * 2 + m2_fl * 4;
    const size_t need_full = need_base + wb_sh * 2;

    short *mcm, *mmc, *zTb, *wb = nullptr;
    float* m2;
    int write_hat;
    if (ws_size >= need_base) {
        char* p = (char*)d_ws;
        mcm = (short*)p;          p += mcm_sh * 2;
        mmc = (short*)p;          p += mmc_sh * 2;
        m2  = (float*)p;          p += m2_fl * 4;
        zTb = (short*)p;          p += zTb_sh * 2;
        if (ws_size >= need_full) wb = (short*)p;
        write_hat = 1;
    } else {
        // fallback: stage mcm+mmc+m2 in the w_hat slot, zTb in z_hat slot,
        // copy w -> w_hat at the end.
        char* p = (char*)w_hat;
        mcm = (short*)p;          p += mcm_sh * 2;
        mmc = (short*)p;          p += mmc_sh * 2;
        m2  = (float*)p;
        zTb = (short*)z_hat;
        write_hat = 0;
    }
    float* simbuf = logw;   // stage sim in the logw slot (softmax rewrites it)

    gather_mem<<<dim3(MP_ / 32, C_ / 64), 256, 0, stream>>>(memory, mcm, mmc);
    transpose_z<<<dim3(C_ / 64, HW_ / 64, N_), 256, 0, stream>>>(z, zTb);
    m2_kernel<<<dim3(MP_ / 256, KCLS), 256, 0, stream>>>(mcm, m2);
    gemm_nt<0><<<dim3(MP_ / 128, HW_ / 128, N_), 256, 0, stream>>>(zTb, mmc, nullptr, cls, m2, simbuf);
    softmax_kernel<<<N_ * HW_, 256, 0, stream>>>(simbuf, w_hat, w, logw, wb, write_hat);
    if (wb)
        gemm_nt<2><<<dim3(HW_ / 128, C_ / 128, N_), 256, 0, stream>>>(mcm, wb, nullptr, cls, m2, z_hat);
    else
        gemm_nt<1><<<dim3(HW_ / 128, C_ / 128, N_), 256, 0, stream>>>(mcm, nullptr, w, cls, m2, z_hat);
    if (!write_hat)
        copy_kernel<<<2048, 256, 0, stream>>>(w, w_hat, (N_ * HW_ * M_) / 4);
}

// Round 4
// 280.348 us; speedup vs baseline: 3.9791x; 1.1002x over previous
//
#include <hip/hip_runtime.h>
#include <hip/hip_bf16.h>
#include <math.h>

#define N_   64
#define C_   512
#define HW_  256
#define M_   2000
#define KCLS 10
#define MP_  2048   // M padded to multiple of 128 (zeros in pad)
// bf16 sim row stride inside the logw fp32 slot: 2000 floats = 4000 shorts
#define SIMS 4000

typedef __attribute__((ext_vector_type(8))) short bf16x8;
typedef __attribute__((ext_vector_type(4))) float f32x4;

__device__ __forceinline__ short f2bf(float x) {
    __hip_bfloat16 b = __float2bfloat16(x);
    return *reinterpret_cast<short*>(&b);
}
__device__ __forceinline__ float bf2f(short s) {
    __hip_bfloat16 b = *reinterpret_cast<__hip_bfloat16*>(&s);
    return __bfloat162float(b);
}

// ---------------------------------------------------------------------------
// memory fp32 [(c*M+m)*10+k] -> mcm bf16 [k][C][MP] (m contig)  and
//                               mmc bf16 [k][MP][C] (c contig), pad m>=2000 = 0
// ---------------------------------------------------------------------------
__global__ __launch_bounds__(256) void gather_mem(const float* __restrict__ mem,
                                                  short* __restrict__ mcm,
                                                  short* __restrict__ mmc) {
    const int m0 = blockIdx.x * 32;
    const int c0 = blockIdx.y * 64;
    __shared__ short tile[KCLS][32][66];
    const int t = threadIdx.x;
    const int mm = t & 31;
    const int m = m0 + mm;
    const int cbase = t >> 5;               // 0..7
    for (int ci = 0; ci < 8; ++ci) {
        const int cl = cbase + ci * 8;      // 0..63
        const int c = c0 + cl;
        short v[KCLS];
        if (m < M_) {
            const float* src = mem + ((size_t)c * M_ + m) * KCLS;
#pragma unroll
            for (int k = 0; k < KCLS; ++k) v[k] = f2bf(src[k]);
        } else {
#pragma unroll
            for (int k = 0; k < KCLS; ++k) v[k] = 0;
        }
#pragma unroll
        for (int k = 0; k < KCLS; ++k) {
            mcm[(size_t)k * (C_ * MP_) + (size_t)c * MP_ + m0 + mm] = v[k];
            tile[k][mm][cl] = v[k];
        }
    }
    __syncthreads();
    const int cc = t & 63;
    const int rbase = t >> 6;               // 0..3
    for (int k = 0; k < KCLS; ++k) {
#pragma unroll
        for (int r = 0; r < 8; ++r) {
            const int mm2 = r * 4 + rbase;
            mmc[(size_t)k * (MP_ * C_) + (size_t)(m0 + mm2) * C_ + c0 + cc] = tile[k][mm2][cc];
        }
    }
}

// ---------------------------------------------------------------------------
// z fp32 [n][c][p] -> zTb bf16 [n][p][c] (c contig)
// ---------------------------------------------------------------------------
__global__ __launch_bounds__(256) void transpose_z(const float* __restrict__ z,
                                                   short* __restrict__ zTb) {
    const int c0 = blockIdx.x * 64;
    const int p0 = blockIdx.y * 64;
    const int n = blockIdx.z;
    const float* zp = z + (size_t)n * C_ * HW_;
    __shared__ short tile[64][70];
    const int t = threadIdx.x;
    const int pp = t & 63;
    const int cb = t >> 6;
#pragma unroll
    for (int i = 0; i < 16; ++i) {
        const int cl = i * 4 + cb;
        tile[cl][pp] = f2bf(zp[(size_t)(c0 + cl) * HW_ + p0 + pp]);
    }
    __syncthreads();
    short* dst = zTb + (size_t)n * HW_ * C_;
    const int cc = t & 63;
    const int pb = t >> 6;
#pragma unroll
    for (int i = 0; i < 16; ++i) {
        const int pl = i * 4 + pb;
        dst[(size_t)(p0 + pl) * C_ + c0 + cc] = tile[cc][pl];
    }
}

// ---------------------------------------------------------------------------
// m2[k][m] = sum_c mcm[k][c][m]^2, padded to MP_ (pad cols give 0)
// ---------------------------------------------------------------------------
__global__ __launch_bounds__(256) void m2_kernel(const short* __restrict__ mcm,
                                                 float* __restrict__ m2) {
    const int m = blockIdx.x * 256 + threadIdx.x;   // 0..2047
    const int k = blockIdx.y;
    const short* B = mcm + (size_t)k * C_ * MP_;
    float s = 0.f;
    for (int c = 0; c < C_; ++c) {
        float v = bf2f(B[(size_t)c * MP_ + m]);
        s = fmaf(v, v, s);
    }
    m2[k * MP_ + m] = s;
}

// ---------------------------------------------------------------------------
// Unified NT MFMA GEMM, 128x128 tile, BK=64, 4 waves, m97 structure,
// XCD-chunked block swizzle, LDS-staged vectorized epilogue stores.
// MODE 0 (sim):       A=zTb[n] (p x 512), B=mmc[kc] (m x 512),
//                     D=sim bf16 aliased in logw slot (row stride SIMS shorts),
//                     epilogue 2x - m2 (m2 padded, no masking)
// MODE 1 (zhat fp32): A=mcm[kc] (c x 2048), B=w fp32 (reg-stage+cvt fallback)
// MODE 2 (zhat bf16): A=mcm[kc] (c x 2048), B=wb bf16 [n] (p x 2048)
// LDS layout [128 rows][8 slots of 16B], slot XOR-swizzled by (row&7):
// gload_lds dest is linear (rule 21) -> pre-swizzle the GLOBAL source chunk.
// ---------------------------------------------------------------------------
template<int MODE>
__global__ __launch_bounds__(256) void gemm_nt(const short* __restrict__ Ab,
                                               const short* __restrict__ Bb,
                                               const float* __restrict__ Bf,
                                               const int* __restrict__ cls,
                                               const float* __restrict__ m2,
                                               float* __restrict__ Db) {
    constexpr int K  = (MODE == 0) ? C_ : MP_;
    constexpr int SA = (MODE == 0) ? C_ : MP_;   // A row stride (elements)
    constexpr int SB = (MODE == 0) ? C_ : MP_;   // B row stride (MODE 0/2)
    constexpr int GX = (MODE == 0) ? 16 : 2;
    constexpr int GY = (MODE == 0) ? 2 : 4;
    constexpr int NWG = GX * GY * N_;
    constexpr int CPX = NWG / 8;

    // XCD-chunked swizzle: blocks with flat%8==x (round-robin XCD x) get a
    // contiguous logical range -> same-n panels resident in one XCD's L2.
    const int flat = blockIdx.x + GX * (blockIdx.y + GY * blockIdx.z);
    const int logical = (flat & 7) * CPX + (flat >> 3);
    const int n  = logical / (GX * GY);
    const int rr = logical % (GX * GY);
    const int by = rr / GX, bx = rr % GX;

    const int kc = cls[n];
    const int rowA0 = by * 128, colB0 = bx * 128;

    const short* A;
    const short* B  = nullptr;
    const float* BF = nullptr;
    if constexpr (MODE == 0) {
        A = Ab + (size_t)n * HW_ * C_;
        B = Bb + (size_t)kc * MP_ * C_;
    } else if constexpr (MODE == 1) {
        A = Ab + (size_t)kc * C_ * MP_;
        BF = Bf + (size_t)n * HW_ * M_;
    } else {
        A = Ab + (size_t)kc * C_ * MP_;
        B = Bb + (size_t)n * HW_ * MP_;
    }

    __shared__ short smem[2 * 128 * 64];
    short* As = smem;
    short* Bs = smem + 128 * 64;

    const int tid = threadIdx.x;
    const int w = tid >> 6, lane = tid & 63;
    const int wr = w >> 1, wc = w & 1;
    const int srow = lane >> 3, sslot = lane & 7;

    f32x4 acc[4][4];
#pragma unroll
    for (int i = 0; i < 4; ++i)
#pragma unroll
        for (int j = 0; j < 4; ++j) acc[i][j] = (f32x4){0.f, 0.f, 0.f, 0.f};

    for (int k0 = 0; k0 < K; k0 += 64) {
        // ---- stage A: 4 x global_load_lds(16B) per wave, pre-swizzled src ----
#pragma unroll
        for (int i = 0; i < 4; ++i) {
            const int row = w * 32 + i * 8 + srow;
            const int chunk = sslot ^ (row & 7);
            const short* src = A + (size_t)(rowA0 + row) * SA + k0 + chunk * 8;
            __builtin_amdgcn_global_load_lds(
                (const __attribute__((address_space(1))) void*)src,
                (__attribute__((address_space(3))) void*)&As[(w * 32 + i * 8) * 64],
                16, 0, 0);
        }
        // ---- stage B ----
        if constexpr (MODE != 1) {
#pragma unroll
            for (int i = 0; i < 4; ++i) {
                const int row = w * 32 + i * 8 + srow;
                const int chunk = sslot ^ (row & 7);
                const short* src = B + (size_t)(colB0 + row) * SB + k0 + chunk * 8;
                __builtin_amdgcn_global_load_lds(
                    (const __attribute__((address_space(1))) void*)src,
                    (__attribute__((address_space(3))) void*)&Bs[(w * 32 + i * 8) * 64],
                    16, 0, 0);
            }
        } else {
#pragma unroll
            for (int i = 0; i < 4; ++i) {
                const int row = w * 32 + i * 8 + srow;
                const int kg = k0 + sslot * 8;
                float4 v0 = {0.f, 0.f, 0.f, 0.f}, v1 = {0.f, 0.f, 0.f, 0.f};
                if (kg < M_) {   // 2000 % 8 == 0: chunk is all-or-nothing
                    const float* s = BF + (size_t)(colB0 + row) * M_ + kg;
                    v0 = *reinterpret_cast<const float4*>(s);
                    v1 = *reinterpret_cast<const float4*>(s + 4);
                }
                bf16x8 bv;
                bv[0] = f2bf(v0.x); bv[1] = f2bf(v0.y); bv[2] = f2bf(v0.z); bv[3] = f2bf(v0.w);
                bv[4] = f2bf(v1.x); bv[5] = f2bf(v1.y); bv[6] = f2bf(v1.z); bv[7] = f2bf(v1.w);
                *reinterpret_cast<bf16x8*>(&Bs[row * 64 + (sslot ^ (row & 7)) * 8]) = bv;
            }
        }
        __syncthreads();
        // ---- compute: 16 ds_read_b128 + 32 MFMA per wave ----
        bf16x8 a[4][2], b[4][2];
#pragma unroll
        for (int i = 0; i < 4; ++i)
#pragma unroll
            for (int kk = 0; kk < 2; ++kk) {
                const int ra = wr * 64 + i * 16 + (lane & 15);
                const int slot = kk * 4 + (lane >> 4);
                a[i][kk] = *reinterpret_cast<const bf16x8*>(&As[ra * 64 + (slot ^ (ra & 7)) * 8]);
                const int rb = wc * 64 + i * 16 + (lane & 15);
                b[i][kk] = *reinterpret_cast<const bf16x8*>(&Bs[rb * 64 + (slot ^ (rb & 7)) * 8]);
            }
#pragma unroll
        for (int i = 0; i < 4; ++i)
#pragma unroll
            for (int j = 0; j < 4; ++j)
#pragma unroll
                for (int kk = 0; kk < 2; ++kk)
                    acc[i][j] = __builtin_amdgcn_mfma_f32_16x16x32_bf16(a[i][kk], b[j][kk], acc[i][j], 0, 0, 0);
        __syncthreads();
    }

    // ---- LDS-staged epilogue: coalesced 16B stores ----
    if constexpr (MODE == 0) {
        // bf16 sim tile 128x128 (32 KB), XOR-swizzled banks
        short* outs = smem;
#pragma unroll
        for (int i = 0; i < 4; ++i)
#pragma unroll
            for (int j = 0; j < 4; ++j) {
                const int col = wc * 64 + j * 16 + (lane & 15);
                const float m2v = m2[kc * MP_ + colB0 + col];
#pragma unroll
                for (int r = 0; r < 4; ++r) {
                    const int row = wr * 64 + i * 16 + (lane >> 4) * 4 + r;
                    outs[row * 128 + (col ^ (((row >> 2) & 7) << 3))] =
                        f2bf(2.f * acc[i][j][r] - m2v);
                }
            }
        __syncthreads();
        short* Ds = (short*)Db;   // logw slot; row stride SIMS shorts (8000 B)
        const size_t rbase = (size_t)n * HW_ + rowA0;
#pragma unroll
        for (int it = 0; it < 8; ++it) {
            const int chunk = tid + it * 256;
            const int row = chunk >> 4, c8 = (chunk & 15) * 8;
            bf16x8 v = *reinterpret_cast<const bf16x8*>(
                &outs[row * 128 + (c8 ^ (((row >> 2) & 7) << 3))]);
            *reinterpret_cast<bf16x8*>(Ds + (rbase + row) * SIMS + colB0 + c8) = v;
        }
    } else {
        // fp32 z_hat tile 128x128 in two 64x128 halves (32 KB each)
        float* outf = (float*)smem;
        float* D = Db + (size_t)n * C_ * HW_;
#pragma unroll
        for (int h = 0; h < 2; ++h) {
            if (wr == h) {
#pragma unroll
                for (int i = 0; i < 4; ++i)
#pragma unroll
                    for (int j = 0; j < 4; ++j) {
                        const int col = wc * 64 + j * 16 + (lane & 15);
#pragma unroll
                        for (int r = 0; r < 4; ++r) {
                            const int row = i * 16 + (lane >> 4) * 4 + r;   // 0..63
                            outf[row * 128 + (col ^ (((row >> 2) & 1) << 4))] = acc[i][j][r];
                        }
                    }
            }
            __syncthreads();
#pragma unroll
            for (int it = 0; it < 8; ++it) {
                const int chunk = tid + it * 256;
                const int row = chunk >> 5, c4 = (chunk & 31) * 4;
                float4 v = *reinterpret_cast<const float4*>(
                    &outf[row * 128 + (c4 ^ (((row >> 2) & 1) << 4))]);
                *reinterpret_cast<float4*>(
                    &D[(size_t)(rowA0 + h * 64 + row) * HW_ + colB0 + c4]) = v;
            }
            __syncthreads();
        }
    }
}

// ---------------------------------------------------------------------------
// Row softmax over m=2000. Reads bf16 sim from the logw slot (block-private
// aliasing: row r occupies the first 4096 B of logw's 8000 B row region),
// writes w_hat (opt), w, logw fp32 and wb bf16 (opt, zero-padded to MP_).
// ---------------------------------------------------------------------------
__global__ __launch_bounds__(256) void softmax_kernel(const short* __restrict__ simb,
                                                      float* __restrict__ w_hat,
                                                      float* __restrict__ w,
                                                      float* __restrict__ logw,
                                                      short* __restrict__ wb,
                                                      int write_hat) {
    const int r = blockIdx.x;
    const int t = threadIdx.x;
    const bool valid = t < (M_ / 8);       // 250 full chunks, 2000%8==0

    float s[8];
    if (valid) {
        bf16x8 v = *reinterpret_cast<const bf16x8*>(simb + (size_t)r * SIMS + t * 8);
#pragma unroll
        for (int i = 0; i < 8; ++i) s[i] = bf2f(v[i]);
    } else {
#pragma unroll
        for (int i = 0; i < 8; ++i) s[i] = -INFINITY;
    }

    float lmax = s[0];
#pragma unroll
    for (int i = 1; i < 8; ++i) lmax = fmaxf(lmax, s[i]);
#pragma unroll
    for (int off = 32; off >= 1; off >>= 1)
        lmax = fmaxf(lmax, __shfl_xor(lmax, off));

    __shared__ float wred[4];
    __shared__ float wsum[4];
    const int wid = t >> 6, lane = t & 63;
    if (lane == 0) wred[wid] = lmax;
    __syncthreads();
    const float gmax = fmaxf(fmaxf(wred[0], wred[1]), fmaxf(wred[2], wred[3]));

    float e[8];
    float lsum = 0.f;
    if (valid) {
#pragma unroll
        for (int i = 0; i < 8; ++i) {
            e[i] = __expf(s[i] - gmax);
            lsum += e[i];
        }
    }
#pragma unroll
    for (int off = 32; off >= 1; off >>= 1)
        lsum += __shfl_xor(lsum, off);
    if (lane == 0) wsum[wid] = lsum;
    __syncthreads();
    const float gsum = wsum[0] + wsum[1] + wsum[2] + wsum[3];
    const float inv = 1.f / gsum;
    const float lg  = __logf(gsum);

    if (valid) {
        const size_t base = (size_t)r * M_ + t * 8;
        float4 w0, w1, l0, l1;
        w0.x = e[0] * inv; w0.y = e[1] * inv; w0.z = e[2] * inv; w0.w = e[3] * inv;
        w1.x = e[4] * inv; w1.y = e[5] * inv; w1.z = e[6] * inv; w1.w = e[7] * inv;
        l0.x = s[0] - gmax - lg; l0.y = s[1] - gmax - lg;
        l0.z = s[2] - gmax - lg; l0.w = s[3] - gmax - lg;
        l1.x = s[4] - gmax - lg; l1.y = s[5] - gmax - lg;
        l1.z = s[6] - gmax - lg; l1.w = s[7] - gmax - lg;
        *reinterpret_cast<float4*>(w + base)     = w0;
        *reinterpret_cast<float4*>(w + base + 4) = w1;
        if (write_hat) {
            *reinterpret_cast<float4*>(w_hat + base)     = w0;
            *reinterpret_cast<float4*>(w_hat + base + 4) = w1;
        }
        *reinterpret_cast<float4*>(logw + base)     = l0;
        *reinterpret_cast<float4*>(logw + base + 4) = l1;
        if (wb) {
            bf16x8 bv;
            bv[0] = f2bf(w0.x); bv[1] = f2bf(w0.y); bv[2] = f2bf(w0.z); bv[3] = f2bf(w0.w);
            bv[4] = f2bf(w1.x); bv[5] = f2bf(w1.y); bv[6] = f2bf(w1.z); bv[7] = f2bf(w1.w);
            *reinterpret_cast<bf16x8*>(wb + (size_t)r * MP_ + t * 8) = bv;
        }
    } else if (wb) {
        bf16x8 zv = {0, 0, 0, 0, 0, 0, 0, 0};
        *reinterpret_cast<bf16x8*>(wb + (size_t)r * MP_ + t * 8) = zv;
    }
}

__global__ __launch_bounds__(256) void copy_kernel(const float* __restrict__ src,
                                                   float* __restrict__ dst, int n4) {
    int i = blockIdx.x * 256 + threadIdx.x;
    int stride = gridDim.x * 256;
    for (; i < n4; i += stride)
        reinterpret_cast<float4*>(dst)[i] = reinterpret_cast<const float4*>(src)[i];
}

// ---------------------------------------------------------------------------
extern "C" void kernel_launch(void* const* d_in, const int* in_sizes, int n_in,
                              void* d_out, int out_size, void* d_ws, size_t ws_size,
                              hipStream_t stream) {
    const float* z      = (const float*)d_in[0];
    const int*   cls    = (const int*)d_in[1];
    const float* memory = (const float*)d_in[2];

    float* out   = (float*)d_out;
    float* z_hat = out;                                  //  8,388,608 fp32
    float* w_hat = z_hat + (size_t)N_ * C_ * HW_;        // 32,768,000
    float* w     = w_hat + (size_t)N_ * HW_ * M_;        // 32,768,000
    float* logw  = w     + (size_t)N_ * HW_ * M_;        // 32,768,000

    const size_t mcm_sh = (size_t)KCLS * C_ * MP_;       // bf16 elems
    const size_t mmc_sh = mcm_sh;
    const size_t zTb_sh = (size_t)N_ * HW_ * C_;
    const size_t wb_sh  = (size_t)N_ * HW_ * MP_;
    const size_t m2_fl  = (size_t)KCLS * MP_;
    const size_t need_base = (mcm_sh + mmc_sh + zTb_sh) * 2 + m2_fl * 4;
    const size_t need_full = need_base + wb_sh * 2;

    short *mcm, *mmc, *zTb, *wb = nullptr;
    float* m2;
    int write_hat;
    if (ws_size >= need_base) {
        char* p = (char*)d_ws;
        mcm = (short*)p;          p += mcm_sh * 2;
        mmc = (short*)p;          p += mmc_sh * 2;
        m2  = (float*)p;          p += m2_fl * 4;
        zTb = (short*)p;          p += zTb_sh * 2;
        if (ws_size >= need_full) wb = (short*)p;
        write_hat = 1;
    } else {
        // fallback: stage mcm+mmc+m2 in the w_hat slot, zTb in z_hat slot,
        // copy w -> w_hat at the end.
        char* p = (char*)w_hat;
        mcm = (short*)p;          p += mcm_sh * 2;
        mmc = (short*)p;          p += mmc_sh * 2;
        m2  = (float*)p;
        zTb = (short*)z_hat;
        write_hat = 0;
    }
    // bf16 sim aliased into the logw slot (block-private row regions)
    short* simb = (short*)logw;

    gather_mem<<<dim3(MP_ / 32, C_ / 64), 256, 0, stream>>>(memory, mcm, mmc);
    transpose_z<<<dim3(C_ / 64, HW_ / 64, N_), 256, 0, stream>>>(z, zTb);
    m2_kernel<<<dim3(MP_ / 256, KCLS), 256, 0, stream>>>(mcm, m2);
    gemm_nt<0><<<dim3(16, 2, N_), 256, 0, stream>>>(zTb, mmc, nullptr, cls, m2, logw);
    softmax_kernel<<<N_ * HW_, 256, 0, stream>>>(simb, w_hat, w, logw, wb, write_hat);
    if (wb)
        gemm_nt<2><<<dim3(2, 4, N_), 256, 0, stream>>>(mcm, wb, nullptr, cls, m2, z_hat);
    else
        gemm_nt<1><<<dim3(2, 4, N_), 256, 0, stream>>>(mcm, nullptr, w, cls, m2, z_hat);
    if (!write_hat)
        copy_kernel<<<2048, 256, 0, stream>>>(w, w_hat, (N_ * HW_ * M_) / 4);
}

// Round 5
// 266.559 us; speedup vs baseline: 4.1850x; 1.0517x over previous
//
#include <hip/hip_runtime.h>
#include <hip/hip_bf16.h>
#include <math.h>

#define N_   64
#define C_   512
#define HW_  256
#define M_   2000
#define KCLS 10
#define MP_  2048   // M padded to multiple of 128 (zeros in pad)
// bf16 sim row stride inside the logw fp32 slot: 2000 floats = 4000 shorts
#define SIMS 4000

typedef __attribute__((ext_vector_type(8))) short bf16x8;
typedef __attribute__((ext_vector_type(4))) float f32x4;

__device__ __forceinline__ short f2bf(float x) {
    __hip_bfloat16 b = __float2bfloat16(x);
    return *reinterpret_cast<short*>(&b);
}
__device__ __forceinline__ float bf2f(short s) {
    __hip_bfloat16 b = *reinterpret_cast<__hip_bfloat16*>(&s);
    return __bfloat162float(b);
}

// ---------------------------------------------------------------------------
// Fused prep:
//  blocks [0,512):   gather memory fp32 [(c*M+m)*10+k] -> mcm bf16 [k][C][MP]
//                    (m contig) and mmc bf16 [k][MP][C] (c contig), pad = 0;
//                    also m2[k][m] += sum_c v^2 (LDS partial + atomicAdd).
//  blocks [512,2560): transpose z fp32 [n][c][p] -> zTb bf16 [n][p][c].
// m2 must be zeroed before launch (hipMemsetAsync).
// ---------------------------------------------------------------------------
#define GATHER_LDS (KCLS * 32 * 66 * 2)
#define PART_LDS   (KCLS * 8 * 32 * 4)

__global__ __launch_bounds__(256) void prep_kernel(const float* __restrict__ mem,
                                                   const float* __restrict__ z,
                                                   short* __restrict__ mcm,
                                                   short* __restrict__ mmc,
                                                   short* __restrict__ zTb,
                                                   float* __restrict__ m2) {
    __shared__ __align__(16) char smem[GATHER_LDS + PART_LDS];
    const int t = threadIdx.x;
    const int bid = blockIdx.x;

    if (bid < 512) {
        // ---------------- gather + m2 ----------------
        short (*tile)[32][66] = reinterpret_cast<short(*)[32][66]>(smem);
        float (*part)[8][32]  = reinterpret_cast<float(*)[8][32]>(smem + GATHER_LDS);
        const int m0 = (bid & 63) * 32;
        const int c0 = (bid >> 6) * 64;
        const int mm = t & 31;
        const int m = m0 + mm;
        const int cbase = t >> 5;               // 0..7
        float msum[KCLS];
#pragma unroll
        for (int k = 0; k < KCLS; ++k) msum[k] = 0.f;
        for (int ci = 0; ci < 8; ++ci) {
            const int cl = cbase + ci * 8;      // 0..63
            const int c = c0 + cl;
            short v[KCLS];
            if (m < M_) {
                const float* src = mem + ((size_t)c * M_ + m) * KCLS;
#pragma unroll
                for (int k = 0; k < KCLS; ++k) v[k] = f2bf(src[k]);
            } else {
#pragma unroll
                for (int k = 0; k < KCLS; ++k) v[k] = 0;
            }
#pragma unroll
            for (int k = 0; k < KCLS; ++k) {
                mcm[(size_t)k * (C_ * MP_) + (size_t)c * MP_ + m] = v[k];
                tile[k][mm][cl] = v[k];
                const float f = bf2f(v[k]);
                msum[k] = fmaf(f, f, msum[k]);
            }
        }
#pragma unroll
        for (int k = 0; k < KCLS; ++k) part[k][cbase][mm] = msum[k];
        __syncthreads();
        for (int idx = t; idx < KCLS * 32; idx += 256) {
            const int k = idx >> 5, mr = idx & 31;
            float s = 0.f;
#pragma unroll
            for (int cb = 0; cb < 8; ++cb) s += part[k][cb][mr];
            atomicAdd(&m2[k * MP_ + m0 + mr], s);
        }
        const int cc = t & 63;
        const int rbase = t >> 6;               // 0..3
        for (int k = 0; k < KCLS; ++k) {
#pragma unroll
            for (int r = 0; r < 8; ++r) {
                const int mm2 = r * 4 + rbase;
                mmc[(size_t)k * (MP_ * C_) + (size_t)(m0 + mm2) * C_ + c0 + cc] =
                    tile[k][mm2][cc];
            }
        }
    } else {
        // ---------------- transpose z ----------------
        short (*tile)[70] = reinterpret_cast<short(*)[70]>(smem);
        const int b = bid - 512;                // 2048 blocks
        const int c0 = (b & 7) * 64;
        const int p0 = ((b >> 3) & 3) * 64;
        const int n = b >> 5;
        const float* zp = z + (size_t)n * C_ * HW_;
        const int pp = t & 63;
        const int cb = t >> 6;
#pragma unroll
        for (int i = 0; i < 16; ++i) {
            const int cl = i * 4 + cb;
            tile[cl][pp] = f2bf(zp[(size_t)(c0 + cl) * HW_ + p0 + pp]);
        }
        __syncthreads();
        short* dst = zTb + (size_t)n * HW_ * C_;
        const int cc = t & 63;
        const int pb = t >> 6;
#pragma unroll
        for (int i = 0; i < 16; ++i) {
            const int pl = i * 4 + pb;
            dst[(size_t)(p0 + pl) * C_ + c0 + cc] = tile[cc][pl];
        }
    }
}

// ---------------------------------------------------------------------------
// Unified NT MFMA GEMM, 128x128 tile, BK=64, 4 waves, m97 structure,
// XCD-chunked block swizzle, LDS-staged vectorized epilogue stores.
// MODE 0 (sim):       A=zTb[n] (p x 512), B=mmc[kc] (m x 512),
//                     D=sim bf16 aliased in logw slot (row stride SIMS shorts),
//                     epilogue 2x - m2 (m2 padded, no masking)
// MODE 1 (zhat fp32): A=mcm[kc] (c x 2048), B=w fp32 (reg-stage+cvt fallback)
// MODE 2 (zhat bf16): A=mcm[kc] (c x 2048), B=wb bf16 [n] (p x 2048)
// LDS layout [128 rows][8 slots of 16B], slot XOR-swizzled by (row&7):
// gload_lds dest is linear (rule 21) -> pre-swizzle the GLOBAL source chunk.
// ---------------------------------------------------------------------------
template<int MODE>
__global__ __launch_bounds__(256) void gemm_nt(const short* __restrict__ Ab,
                                               const short* __restrict__ Bb,
                                               const float* __restrict__ Bf,
                                               const int* __restrict__ cls,
                                               const float* __restrict__ m2,
                                               float* __restrict__ Db) {
    constexpr int K  = (MODE == 0) ? C_ : MP_;
    constexpr int SA = (MODE == 0) ? C_ : MP_;   // A row stride (elements)
    constexpr int SB = (MODE == 0) ? C_ : MP_;   // B row stride (MODE 0/2)
    constexpr int GX = (MODE == 0) ? 16 : 2;
    constexpr int GY = (MODE == 0) ? 2 : 4;
    constexpr int NWG = GX * GY * N_;
    constexpr int CPX = NWG / 8;

    // XCD-chunked swizzle: blocks with flat%8==x (round-robin XCD x) get a
    // contiguous logical range -> same-n panels resident in one XCD's L2.
    const int flat = blockIdx.x + GX * (blockIdx.y + GY * blockIdx.z);
    const int logical = (flat & 7) * CPX + (flat >> 3);
    const int n  = logical / (GX * GY);
    const int rr = logical % (GX * GY);
    const int by = rr / GX, bx = rr % GX;

    const int kc = cls[n];
    const int rowA0 = by * 128, colB0 = bx * 128;

    const short* A;
    const short* B  = nullptr;
    const float* BF = nullptr;
    if constexpr (MODE == 0) {
        A = Ab + (size_t)n * HW_ * C_;
        B = Bb + (size_t)kc * MP_ * C_;
    } else if constexpr (MODE == 1) {
        A = Ab + (size_t)kc * C_ * MP_;
        BF = Bf + (size_t)n * HW_ * M_;
    } else {
        A = Ab + (size_t)kc * C_ * MP_;
        B = Bb + (size_t)n * HW_ * MP_;
    }

    __shared__ short smem[2 * 128 * 64];
    short* As = smem;
    short* Bs = smem + 128 * 64;

    const int tid = threadIdx.x;
    const int w = tid >> 6, lane = tid & 63;
    const int wr = w >> 1, wc = w & 1;
    const int srow = lane >> 3, sslot = lane & 7;

    f32x4 acc[4][4];
#pragma unroll
    for (int i = 0; i < 4; ++i)
#pragma unroll
        for (int j = 0; j < 4; ++j) acc[i][j] = (f32x4){0.f, 0.f, 0.f, 0.f};

    for (int k0 = 0; k0 < K; k0 += 64) {
        // ---- stage A: 4 x global_load_lds(16B) per wave, pre-swizzled src ----
#pragma unroll
        for (int i = 0; i < 4; ++i) {
            const int row = w * 32 + i * 8 + srow;
            const int chunk = sslot ^ (row & 7);
            const short* src = A + (size_t)(rowA0 + row) * SA + k0 + chunk * 8;
            __builtin_amdgcn_global_load_lds(
                (const __attribute__((address_space(1))) void*)src,
                (__attribute__((address_space(3))) void*)&As[(w * 32 + i * 8) * 64],
                16, 0, 0);
        }
        // ---- stage B ----
        if constexpr (MODE != 1) {
#pragma unroll
            for (int i = 0; i < 4; ++i) {
                const int row = w * 32 + i * 8 + srow;
                const int chunk = sslot ^ (row & 7);
                const short* src = B + (size_t)(colB0 + row) * SB + k0 + chunk * 8;
                __builtin_amdgcn_global_load_lds(
                    (const __attribute__((address_space(1))) void*)src,
                    (__attribute__((address_space(3))) void*)&Bs[(w * 32 + i * 8) * 64],
                    16, 0, 0);
            }
        } else {
#pragma unroll
            for (int i = 0; i < 4; ++i) {
                const int row = w * 32 + i * 8 + srow;
                const int kg = k0 + sslot * 8;
                float4 v0 = {0.f, 0.f, 0.f, 0.f}, v1 = {0.f, 0.f, 0.f, 0.f};
                if (kg < M_) {   // 2000 % 8 == 0: chunk is all-or-nothing
                    const float* s = BF + (size_t)(colB0 + row) * M_ + kg;
                    v0 = *reinterpret_cast<const float4*>(s);
                    v1 = *reinterpret_cast<const float4*>(s + 4);
                }
                bf16x8 bv;
                bv[0] = f2bf(v0.x); bv[1] = f2bf(v0.y); bv[2] = f2bf(v0.z); bv[3] = f2bf(v0.w);
                bv[4] = f2bf(v1.x); bv[5] = f2bf(v1.y); bv[6] = f2bf(v1.z); bv[7] = f2bf(v1.w);
                *reinterpret_cast<bf16x8*>(&Bs[row * 64 + (sslot ^ (row & 7)) * 8]) = bv;
            }
        }
        __syncthreads();
        // ---- compute: 16 ds_read_b128 + 32 MFMA per wave ----
        bf16x8 a[4][2], b[4][2];
#pragma unroll
        for (int i = 0; i < 4; ++i)
#pragma unroll
            for (int kk = 0; kk < 2; ++kk) {
                const int ra = wr * 64 + i * 16 + (lane & 15);
                const int slot = kk * 4 + (lane >> 4);
                a[i][kk] = *reinterpret_cast<const bf16x8*>(&As[ra * 64 + (slot ^ (ra & 7)) * 8]);
                const int rb = wc * 64 + i * 16 + (lane & 15);
                b[i][kk] = *reinterpret_cast<const bf16x8*>(&Bs[rb * 64 + (slot ^ (rb & 7)) * 8]);
            }
#pragma unroll
        for (int i = 0; i < 4; ++i)
#pragma unroll
            for (int j = 0; j < 4; ++j)
#pragma unroll
                for (int kk = 0; kk < 2; ++kk)
                    acc[i][j] = __builtin_amdgcn_mfma_f32_16x16x32_bf16(a[i][kk], b[j][kk], acc[i][j], 0, 0, 0);
        __syncthreads();
    }

    // ---- LDS-staged epilogue: coalesced 16B stores ----
    if constexpr (MODE == 0) {
        // bf16 sim tile 128x128 (32 KB), XOR-swizzled banks
        short* outs = smem;
#pragma unroll
        for (int i = 0; i < 4; ++i)
#pragma unroll
            for (int j = 0; j < 4; ++j) {
                const int col = wc * 64 + j * 16 + (lane & 15);
                const float m2v = m2[kc * MP_ + colB0 + col];
#pragma unroll
                for (int r = 0; r < 4; ++r) {
                    const int row = wr * 64 + i * 16 + (lane >> 4) * 4 + r;
                    outs[row * 128 + (col ^ (((row >> 2) & 7) << 3))] =
                        f2bf(2.f * acc[i][j][r] - m2v);
                }
            }
        __syncthreads();
        short* Ds = (short*)Db;   // logw slot; row stride SIMS shorts (8000 B)
        const size_t rbase = (size_t)n * HW_ + rowA0;
#pragma unroll
        for (int it = 0; it < 8; ++it) {
            const int chunk = tid + it * 256;
            const int row = chunk >> 4, c8 = (chunk & 15) * 8;
            bf16x8 v = *reinterpret_cast<const bf16x8*>(
                &outs[row * 128 + (c8 ^ (((row >> 2) & 7) << 3))]);
            *reinterpret_cast<bf16x8*>(Ds + (rbase + row) * SIMS + colB0 + c8) = v;
        }
    } else {
        // fp32 z_hat tile 128x128 in two 64x128 halves (32 KB each)
        float* outf = (float*)smem;
        float* D = Db + (size_t)n * C_ * HW_;
#pragma unroll
        for (int h = 0; h < 2; ++h) {
            if (wr == h) {
#pragma unroll
                for (int i = 0; i < 4; ++i)
#pragma unroll
                    for (int j = 0; j < 4; ++j) {
                        const int col = wc * 64 + j * 16 + (lane & 15);
#pragma unroll
                        for (int r = 0; r < 4; ++r) {
                            const int row = i * 16 + (lane >> 4) * 4 + r;   // 0..63
                            outf[row * 128 + (col ^ (((row >> 2) & 1) << 4))] = acc[i][j][r];
                        }
                    }
            }
            __syncthreads();
#pragma unroll
            for (int it = 0; it < 8; ++it) {
                const int chunk = tid + it * 256;
                const int row = chunk >> 5, c4 = (chunk & 31) * 4;
                float4 v = *reinterpret_cast<const float4*>(
                    &outf[row * 128 + (c4 ^ (((row >> 2) & 1) << 4))]);
                *reinterpret_cast<float4*>(
                    &D[(size_t)(rowA0 + h * 64 + row) * HW_ + colB0 + c4]) = v;
            }
            __syncthreads();
        }
    }
}

// ---------------------------------------------------------------------------
// Row softmax over m=2000. Reads bf16 sim from the logw slot (block-private
// aliasing: row r occupies the first 4096 B of logw's 8000 B row region),
// writes w_hat (opt), w, logw fp32 and wb bf16 (opt, zero-padded to MP_).
// ---------------------------------------------------------------------------
__global__ __launch_bounds__(256) void softmax_kernel(const short* __restrict__ simb,
                                                      float* __restrict__ w_hat,
                                                      float* __restrict__ w,
                                                      float* __restrict__ logw,
                                                      short* __restrict__ wb,
                                                      int write_hat) {
    const int r = blockIdx.x;
    const int t = threadIdx.x;
    const bool valid = t < (M_ / 8);       // 250 full chunks, 2000%8==0

    float s[8];
    if (valid) {
        bf16x8 v = *reinterpret_cast<const bf16x8*>(simb + (size_t)r * SIMS + t * 8);
#pragma unroll
        for (int i = 0; i < 8; ++i) s[i] = bf2f(v[i]);
    } else {
#pragma unroll
        for (int i = 0; i < 8; ++i) s[i] = -INFINITY;
    }

    float lmax = s[0];
#pragma unroll
    for (int i = 1; i < 8; ++i) lmax = fmaxf(lmax, s[i]);
#pragma unroll
    for (int off = 32; off >= 1; off >>= 1)
        lmax = fmaxf(lmax, __shfl_xor(lmax, off));

    __shared__ float wred[4];
    __shared__ float wsum[4];
    const int wid = t >> 6, lane = t & 63;
    if (lane == 0) wred[wid] = lmax;
    __syncthreads();
    const float gmax = fmaxf(fmaxf(wred[0], wred[1]), fmaxf(wred[2], wred[3]));

    float e[8];
    float lsum = 0.f;
    if (valid) {
#pragma unroll
        for (int i = 0; i < 8; ++i) {
            e[i] = __expf(s[i] - gmax);
            lsum += e[i];
        }
    }
#pragma unroll
    for (int off = 32; off >= 1; off >>= 1)
        lsum += __shfl_xor(lsum, off);
    if (lane == 0) wsum[wid] = lsum;
    __syncthreads();
    const float gsum = wsum[0] + wsum[1] + wsum[2] + wsum[3];
    const float inv = 1.f / gsum;
    const float lg  = __logf(gsum);

    if (valid) {
        const size_t base = (size_t)r * M_ + t * 8;
        float4 w0, w1, l0, l1;
        w0.x = e[0] * inv; w0.y = e[1] * inv; w0.z = e[2] * inv; w0.w = e[3] * inv;
        w1.x = e[4] * inv; w1.y = e[5] * inv; w1.z = e[6] * inv; w1.w = e[7] * inv;
        l0.x = s[0] - gmax - lg; l0.y = s[1] - gmax - lg;
        l0.z = s[2] - gmax - lg; l0.w = s[3] - gmax - lg;
        l1.x = s[4] - gmax - lg; l1.y = s[5] - gmax - lg;
        l1.z = s[6] - gmax - lg; l1.w = s[7] - gmax - lg;
        *reinterpret_cast<float4*>(w + base)     = w0;
        *reinterpret_cast<float4*>(w + base + 4) = w1;
        if (write_hat) {
            *reinterpret_cast<float4*>(w_hat + base)     = w0;
            *reinterpret_cast<float4*>(w_hat + base + 4) = w1;
        }
        *reinterpret_cast<float4*>(logw + base)     = l0;
        *reinterpret_cast<float4*>(logw + base + 4) = l1;
        if (wb) {
            bf16x8 bv;
            bv[0] = f2bf(w0.x); bv[1] = f2bf(w0.y); bv[2] = f2bf(w0.z); bv[3] = f2bf(w0.w);
            bv[4] = f2bf(w1.x); bv[5] = f2bf(w1.y); bv[6] = f2bf(w1.z); bv[7] = f2bf(w1.w);
            *reinterpret_cast<bf16x8*>(wb + (size_t)r * MP_ + t * 8) = bv;
        }
    } else if (wb) {
        bf16x8 zv = {0, 0, 0, 0, 0, 0, 0, 0};
        *reinterpret_cast<bf16x8*>(wb + (size_t)r * MP_ + t * 8) = zv;
    }
}

__global__ __launch_bounds__(256) void copy_kernel(const float* __restrict__ src,
                                                   float* __restrict__ dst, int n4) {
    int i = blockIdx.x * 256 + threadIdx.x;
    int stride = gridDim.x * 256;
    for (; i < n4; i += stride)
        reinterpret_cast<float4*>(dst)[i] = reinterpret_cast<const float4*>(src)[i];
}

// ---------------------------------------------------------------------------
extern "C" void kernel_launch(void* const* d_in, const int* in_sizes, int n_in,
                              void* d_out, int out_size, void* d_ws, size_t ws_size,
                              hipStream_t stream) {
    const float* z      = (const float*)d_in[0];
    const int*   cls    = (const int*)d_in[1];
    const float* memory = (const float*)d_in[2];

    float* out   = (float*)d_out;
    float* z_hat = out;                                  //  8,388,608 fp32
    float* w_hat = z_hat + (size_t)N_ * C_ * HW_;        // 32,768,000
    float* w     = w_hat + (size_t)N_ * HW_ * M_;        // 32,768,000
    float* logw  = w     + (size_t)N_ * HW_ * M_;        // 32,768,000

    const size_t mcm_sh = (size_t)KCLS * C_ * MP_;       // bf16 elems
    const size_t mmc_sh = mcm_sh;
    const size_t zTb_sh = (size_t)N_ * HW_ * C_;
    const size_t wb_sh  = (size_t)N_ * HW_ * MP_;
    const size_t m2_fl  = (size_t)KCLS * MP_;
    const size_t need_base = (mcm_sh + mmc_sh + zTb_sh) * 2 + m2_fl * 4;
    const size_t need_full = need_base + wb_sh * 2;

    short *mcm, *mmc, *zTb, *wb = nullptr;
    float* m2;
    int write_hat;
    if (ws_size >= need_base) {
        char* p = (char*)d_ws;
        mcm = (short*)p;          p += mcm_sh * 2;
        mmc = (short*)p;          p += mmc_sh * 2;
        m2  = (float*)p;          p += m2_fl * 4;
        zTb = (short*)p;          p += zTb_sh * 2;
        if (ws_size >= need_full) wb = (short*)p;
        write_hat = 1;
    } else {
        // fallback: stage mcm+mmc+m2 in the w_hat slot, zTb in z_hat slot,
        // copy w -> w_hat at the end.
        char* p = (char*)w_hat;
        mcm = (short*)p;          p += mcm_sh * 2;
        mmc = (short*)p;          p += mmc_sh * 2;
        m2  = (float*)p;
        zTb = (short*)z_hat;
        write_hat = 0;
    }
    // bf16 sim aliased into the logw slot (block-private row regions)
    short* simb = (short*)logw;

    hipMemsetAsync(m2, 0, m2_fl * sizeof(float), stream);
    prep_kernel<<<2560, 256, 0, stream>>>(memory, z, mcm, mmc, zTb, m2);
    gemm_nt<0><<<dim3(16, 2, N_), 256, 0, stream>>>(zTb, mmc, nullptr, cls, m2, logw);
    softmax_kernel<<<N_ * HW_, 256, 0, stream>>>(simb, w_hat, w, logw, wb, write_hat);
    if (wb)
        gemm_nt<2><<<dim3(2, 4, N_), 256, 0, stream>>>(mcm, wb, nullptr, cls, m2, z_hat);
    else
        gemm_nt<1><<<dim3(2, 4, N_), 256, 0, stream>>>(mcm, nullptr, w, cls, m2, z_hat);
    if (!write_hat)
        copy_kernel<<<2048, 256, 0, stream>>>(w, w_hat, (N_ * HW_ * M_) / 4);
}

// Round 6
// 263.028 us; speedup vs baseline: 4.2411x; 1.0134x over previous
//
#include <hip/hip_runtime.h>
#include <hip/hip_bf16.h>
#include <math.h>

#define N_   64
#define C_   512
#define HW_  256
#define M_   2000
#define KCLS 10
#define MP_  2048   // M padded to multiple of 128 (zeros in pad)
// bf16 sim row stride inside the logw fp32 slot: 2000 floats = 4000 shorts
#define SIMS 4000

typedef __attribute__((ext_vector_type(8))) short bf16x8;
typedef __attribute__((ext_vector_type(4))) float f32x4;

__device__ __forceinline__ short f2bf(float x) {
    __hip_bfloat16 b = __float2bfloat16(x);
    return *reinterpret_cast<short*>(&b);
}
__device__ __forceinline__ float bf2f(short s) {
    __hip_bfloat16 b = *reinterpret_cast<__hip_bfloat16*>(&s);
    return __bfloat162float(b);
}

// ---------------------------------------------------------------------------
// Fused prep:
//  blocks [0,512):    gather memory fp32 [(c*M+m)*10+k] -> mcm bf16 [k][C][MP]
//                     (m contig) and mmc bf16 [k][MP][C] (c contig), pad = 0;
//                     also m2[k][m] += sum_c v^2 (LDS partial + atomicAdd).
//  blocks [512,2560): transpose z fp32 [n][c][p] -> zTb bf16 [n][p][c].
//  block 2560:        stable counting-sort of n by cls[n] -> perm[64]
//                     (class-sorted n order gives per-XCD L2 panel locality).
// m2 must be zeroed before launch (hipMemsetAsync).
// ---------------------------------------------------------------------------
#define GATHER_LDS (KCLS * 32 * 66 * 2)
#define PART_LDS   (KCLS * 8 * 32 * 4)

__global__ __launch_bounds__(256) void prep_kernel(const float* __restrict__ mem,
                                                   const float* __restrict__ z,
                                                   const int* __restrict__ cls,
                                                   short* __restrict__ mcm,
                                                   short* __restrict__ mmc,
                                                   short* __restrict__ zTb,
                                                   float* __restrict__ m2,
                                                   int* __restrict__ perm) {
    __shared__ __align__(16) char smem[GATHER_LDS + PART_LDS];
    const int t = threadIdx.x;
    const int bid = blockIdx.x;

    if (bid < 512) {
        // ---------------- gather + m2 ----------------
        short (*tile)[32][66] = reinterpret_cast<short(*)[32][66]>(smem);
        float (*part)[8][32]  = reinterpret_cast<float(*)[8][32]>(smem + GATHER_LDS);
        const int m0 = (bid & 63) * 32;
        const int c0 = (bid >> 6) * 64;
        const int mm = t & 31;
        const int m = m0 + mm;
        const int cbase = t >> 5;               // 0..7
        float msum[KCLS];
#pragma unroll
        for (int k = 0; k < KCLS; ++k) msum[k] = 0.f;
        for (int ci = 0; ci < 8; ++ci) {
            const int cl = cbase + ci * 8;      // 0..63
            const int c = c0 + cl;
            short v[KCLS];
            if (m < M_) {
                const float* src = mem + ((size_t)c * M_ + m) * KCLS;
#pragma unroll
                for (int k = 0; k < KCLS; ++k) v[k] = f2bf(src[k]);
            } else {
#pragma unroll
                for (int k = 0; k < KCLS; ++k) v[k] = 0;
            }
#pragma unroll
            for (int k = 0; k < KCLS; ++k) {
                mcm[(size_t)k * (C_ * MP_) + (size_t)c * MP_ + m] = v[k];
                tile[k][mm][cl] = v[k];
                const float f = bf2f(v[k]);
                msum[k] = fmaf(f, f, msum[k]);
            }
        }
#pragma unroll
        for (int k = 0; k < KCLS; ++k) part[k][cbase][mm] = msum[k];
        __syncthreads();
        for (int idx = t; idx < KCLS * 32; idx += 256) {
            const int k = idx >> 5, mr = idx & 31;
            float s = 0.f;
#pragma unroll
            for (int cb = 0; cb < 8; ++cb) s += part[k][cb][mr];
            atomicAdd(&m2[k * MP_ + m0 + mr], s);
        }
        const int cc = t & 63;
        const int rbase = t >> 6;               // 0..3
        for (int k = 0; k < KCLS; ++k) {
#pragma unroll
            for (int r = 0; r < 8; ++r) {
                const int mm2 = r * 4 + rbase;
                mmc[(size_t)k * (MP_ * C_) + (size_t)(m0 + mm2) * C_ + c0 + cc] =
                    tile[k][mm2][cc];
            }
        }
    } else if (bid < 2560) {
        // ---------------- transpose z ----------------
        short (*tile)[70] = reinterpret_cast<short(*)[70]>(smem);
        const int b = bid - 512;                // 2048 blocks
        const int c0 = (b & 7) * 64;
        const int p0 = ((b >> 3) & 3) * 64;
        const int n = b >> 5;
        const float* zp = z + (size_t)n * C_ * HW_;
        const int pp = t & 63;
        const int cb = t >> 6;
#pragma unroll
        for (int i = 0; i < 16; ++i) {
            const int cl = i * 4 + cb;
            tile[cl][pp] = f2bf(zp[(size_t)(c0 + cl) * HW_ + p0 + pp]);
        }
        __syncthreads();
        short* dst = zTb + (size_t)n * HW_ * C_;
        const int cc = t & 63;
        const int pb = t >> 6;
#pragma unroll
        for (int i = 0; i < 16; ++i) {
            const int pl = i * 4 + pb;
            dst[(size_t)(p0 + pl) * C_ + c0 + cc] = tile[cc][pl];
        }
    } else {
        // ---------------- class-sort perm ----------------
        int* lcls = reinterpret_cast<int*>(smem);
        if (t < N_) lcls[t] = cls[t];
        __syncthreads();
        if (t == 0) {
            int cnt[KCLS], pos[KCLS];
#pragma unroll
            for (int k = 0; k < KCLS; ++k) cnt[k] = 0;
            for (int n = 0; n < N_; ++n) cnt[lcls[n]]++;
            int acc = 0;
#pragma unroll
            for (int k = 0; k < KCLS; ++k) { pos[k] = acc; acc += cnt[k]; }
            for (int n = 0; n < N_; ++n) perm[pos[lcls[n]]++] = n;
        }
    }
}

// ---------------------------------------------------------------------------
// Unified NT MFMA GEMM, 128x128 tile, BK=64, 4 waves, m97 structure,
// XCD-chunked block swizzle over CLASS-SORTED n (perm), LDS-staged epilogues.
// MODE 0 (sim):       A=zTb[n] (p x 512), B=mmc[kc] (m x 512),
//                     D=sim bf16 aliased in logw slot (row stride SIMS shorts),
//                     epilogue 2x - m2 (m2 padded, no masking)
// MODE 1 (zhat fp32): A=mcm[kc] (c x 2048), B=w fp32 (reg-stage+cvt fallback)
// MODE 2 (zhat bf16): A=mcm[kc] (c x 2048), B=wb bf16 [n] (p x 2048)
// LDS layout [128 rows][8 slots of 16B], slot XOR-swizzled by (row&7):
// gload_lds dest is linear (rule 21) -> pre-swizzle the GLOBAL source chunk.
// ---------------------------------------------------------------------------
template<int MODE>
__global__ __launch_bounds__(256) void gemm_nt(const short* __restrict__ Ab,
                                               const short* __restrict__ Bb,
                                               const float* __restrict__ Bf,
                                               const int* __restrict__ cls,
                                               const int* __restrict__ perm,
                                               const float* __restrict__ m2,
                                               float* __restrict__ Db) {
    constexpr int K  = (MODE == 0) ? C_ : MP_;
    constexpr int SA = (MODE == 0) ? C_ : MP_;   // A row stride (elements)
    constexpr int SB = (MODE == 0) ? C_ : MP_;   // B row stride (MODE 0/2)
    constexpr int GX = (MODE == 0) ? 16 : 2;
    constexpr int GY = (MODE == 0) ? 2 : 4;
    constexpr int NWG = GX * GY * N_;
    constexpr int CPX = NWG / 8;

    // XCD-chunked swizzle: blocks with flat%8==x (round-robin XCD x) get a
    // contiguous logical range; logical n mapped through class-sorted perm
    // -> same-class panels resident in one XCD's L2.
    const int flat = blockIdx.x + GX * (blockIdx.y + GY * blockIdx.z);
    const int logical = (flat & 7) * CPX + (flat >> 3);
    const int nl = logical / (GX * GY);
    const int n  = perm[nl];
    const int rr = logical % (GX * GY);
    const int by = rr / GX, bx = rr % GX;

    const int kc = cls[n];
    const int rowA0 = by * 128, colB0 = bx * 128;

    const short* A;
    const short* B  = nullptr;
    const float* BF = nullptr;
    if constexpr (MODE == 0) {
        A = Ab + (size_t)n * HW_ * C_;
        B = Bb + (size_t)kc * MP_ * C_;
    } else if constexpr (MODE == 1) {
        A = Ab + (size_t)kc * C_ * MP_;
        BF = Bf + (size_t)n * HW_ * M_;
    } else {
        A = Ab + (size_t)kc * C_ * MP_;
        B = Bb + (size_t)n * HW_ * MP_;
    }

    __shared__ short smem[2 * 128 * 64];
    short* As = smem;
    short* Bs = smem + 128 * 64;

    const int tid = threadIdx.x;
    const int w = tid >> 6, lane = tid & 63;
    const int wr = w >> 1, wc = w & 1;
    const int srow = lane >> 3, sslot = lane & 7;

    f32x4 acc[4][4];
#pragma unroll
    for (int i = 0; i < 4; ++i)
#pragma unroll
        for (int j = 0; j < 4; ++j) acc[i][j] = (f32x4){0.f, 0.f, 0.f, 0.f};

    for (int k0 = 0; k0 < K; k0 += 64) {
        // ---- stage A: 4 x global_load_lds(16B) per wave, pre-swizzled src ----
#pragma unroll
        for (int i = 0; i < 4; ++i) {
            const int row = w * 32 + i * 8 + srow;
            const int chunk = sslot ^ (row & 7);
            const short* src = A + (size_t)(rowA0 + row) * SA + k0 + chunk * 8;
            __builtin_amdgcn_global_load_lds(
                (const __attribute__((address_space(1))) void*)src,
                (__attribute__((address_space(3))) void*)&As[(w * 32 + i * 8) * 64],
                16, 0, 0);
        }
        // ---- stage B ----
        if constexpr (MODE != 1) {
#pragma unroll
            for (int i = 0; i < 4; ++i) {
                const int row = w * 32 + i * 8 + srow;
                const int chunk = sslot ^ (row & 7);
                const short* src = B + (size_t)(colB0 + row) * SB + k0 + chunk * 8;
                __builtin_amdgcn_global_load_lds(
                    (const __attribute__((address_space(1))) void*)src,
                    (__attribute__((address_space(3))) void*)&Bs[(w * 32 + i * 8) * 64],
                    16, 0, 0);
            }
        } else {
#pragma unroll
            for (int i = 0; i < 4; ++i) {
                const int row = w * 32 + i * 8 + srow;
                const int kg = k0 + sslot * 8;
                float4 v0 = {0.f, 0.f, 0.f, 0.f}, v1 = {0.f, 0.f, 0.f, 0.f};
                if (kg < M_) {   // 2000 % 8 == 0: chunk is all-or-nothing
                    const float* s = BF + (size_t)(colB0 + row) * M_ + kg;
                    v0 = *reinterpret_cast<const float4*>(s);
                    v1 = *reinterpret_cast<const float4*>(s + 4);
                }
                bf16x8 bv;
                bv[0] = f2bf(v0.x); bv[1] = f2bf(v0.y); bv[2] = f2bf(v0.z); bv[3] = f2bf(v0.w);
                bv[4] = f2bf(v1.x); bv[5] = f2bf(v1.y); bv[6] = f2bf(v1.z); bv[7] = f2bf(v1.w);
                *reinterpret_cast<bf16x8*>(&Bs[row * 64 + (sslot ^ (row & 7)) * 8]) = bv;
            }
        }
        __syncthreads();
        // ---- compute: 16 ds_read_b128 + 32 MFMA per wave ----
        bf16x8 a[4][2], b[4][2];
#pragma unroll
        for (int i = 0; i < 4; ++i)
#pragma unroll
            for (int kk = 0; kk < 2; ++kk) {
                const int ra = wr * 64 + i * 16 + (lane & 15);
                const int slot = kk * 4 + (lane >> 4);
                a[i][kk] = *reinterpret_cast<const bf16x8*>(&As[ra * 64 + (slot ^ (ra & 7)) * 8]);
                const int rb = wc * 64 + i * 16 + (lane & 15);
                b[i][kk] = *reinterpret_cast<const bf16x8*>(&Bs[rb * 64 + (slot ^ (rb & 7)) * 8]);
            }
#pragma unroll
        for (int i = 0; i < 4; ++i)
#pragma unroll
            for (int j = 0; j < 4; ++j)
#pragma unroll
                for (int kk = 0; kk < 2; ++kk)
                    acc[i][j] = __builtin_amdgcn_mfma_f32_16x16x32_bf16(a[i][kk], b[j][kk], acc[i][j], 0, 0, 0);
        __syncthreads();
    }

    // ---- LDS-staged epilogue: coalesced 16B stores ----
    if constexpr (MODE == 0) {
        // bf16 sim tile 128x128 (32 KB), XOR-swizzled banks
        short* outs = smem;
#pragma unroll
        for (int i = 0; i < 4; ++i)
#pragma unroll
            for (int j = 0; j < 4; ++j) {
                const int col = wc * 64 + j * 16 + (lane & 15);
                const float m2v = m2[kc * MP_ + colB0 + col];
#pragma unroll
                for (int r = 0; r < 4; ++r) {
                    const int row = wr * 64 + i * 16 + (lane >> 4) * 4 + r;
                    outs[row * 128 + (col ^ (((row >> 2) & 7) << 3))] =
                        f2bf(2.f * acc[i][j][r] - m2v);
                }
            }
        __syncthreads();
        short* Ds = (short*)Db;   // logw slot; row stride SIMS shorts (8000 B)
        const size_t rbase = (size_t)n * HW_ + rowA0;
#pragma unroll
        for (int it = 0; it < 8; ++it) {
            const int chunk = tid + it * 256;
            const int row = chunk >> 4, c8 = (chunk & 15) * 8;
            bf16x8 v = *reinterpret_cast<const bf16x8*>(
                &outs[row * 128 + (c8 ^ (((row >> 2) & 7) << 3))]);
            *reinterpret_cast<bf16x8*>(Ds + (rbase + row) * SIMS + colB0 + c8) = v;
        }
    } else {
        // fp32 z_hat tile 128x128 in two 64x128 halves (32 KB each)
        float* outf = (float*)smem;
        float* D = Db + (size_t)n * C_ * HW_;
#pragma unroll
        for (int h = 0; h < 2; ++h) {
            if (wr == h) {
#pragma unroll
                for (int i = 0; i < 4; ++i)
#pragma unroll
                    for (int j = 0; j < 4; ++j) {
                        const int col = wc * 64 + j * 16 + (lane & 15);
#pragma unroll
                        for (int r = 0; r < 4; ++r) {
                            const int row = i * 16 + (lane >> 4) * 4 + r;   // 0..63
                            outf[row * 128 + (col ^ (((row >> 2) & 1) << 4))] = acc[i][j][r];
                        }
                    }
            }
            __syncthreads();
#pragma unroll
            for (int it = 0; it < 8; ++it) {
                const int chunk = tid + it * 256;
                const int row = chunk >> 5, c4 = (chunk & 31) * 4;
                float4 v = *reinterpret_cast<const float4*>(
                    &outf[row * 128 + (c4 ^ (((row >> 2) & 1) << 4))]);
                *reinterpret_cast<float4*>(
                    &D[(size_t)(rowA0 + h * 64 + row) * HW_ + colB0 + c4]) = v;
            }
            __syncthreads();
        }
    }
}

// ---------------------------------------------------------------------------
// Row softmax over m=2000. Reads bf16 sim from the logw slot (block-private
// aliasing: row r occupies the first 4096 B of logw's 8000 B row region),
// writes w_hat (opt), w, logw fp32 and wb bf16 (opt, zero-padded to MP_).
// ---------------------------------------------------------------------------
__global__ __launch_bounds__(256) void softmax_kernel(const short* __restrict__ simb,
                                                      float* __restrict__ w_hat,
                                                      float* __restrict__ w,
                                                      float* __restrict__ logw,
                                                      short* __restrict__ wb,
                                                      int write_hat) {
    const int r = blockIdx.x;
    const int t = threadIdx.x;
    const bool valid = t < (M_ / 8);       // 250 full chunks, 2000%8==0

    float s[8];
    if (valid) {
        bf16x8 v = *reinterpret_cast<const bf16x8*>(simb + (size_t)r * SIMS + t * 8);
#pragma unroll
        for (int i = 0; i < 8; ++i) s[i] = bf2f(v[i]);
    } else {
#pragma unroll
        for (int i = 0; i < 8; ++i) s[i] = -INFINITY;
    }

    float lmax = s[0];
#pragma unroll
    for (int i = 1; i < 8; ++i) lmax = fmaxf(lmax, s[i]);
#pragma unroll
    for (int off = 32; off >= 1; off >>= 1)
        lmax = fmaxf(lmax, __shfl_xor(lmax, off));

    __shared__ float wred[4];
    __shared__ float wsum[4];
    const int wid = t >> 6, lane = t & 63;
    if (lane == 0) wred[wid] = lmax;
    __syncthreads();
    const float gmax = fmaxf(fmaxf(wred[0], wred[1]), fmaxf(wred[2], wred[3]));

    float e[8];
    float lsum = 0.f;
    if (valid) {
#pragma unroll
        for (int i = 0; i < 8; ++i) {
            e[i] = __expf(s[i] - gmax);
            lsum += e[i];
        }
    }
#pragma unroll
    for (int off = 32; off >= 1; off >>= 1)
        lsum += __shfl_xor(lsum, off);
    if (lane == 0) wsum[wid] = lsum;
    __syncthreads();
    const float gsum = wsum[0] + wsum[1] + wsum[2] + wsum[3];
    const float inv = 1.f / gsum;
    const float lg  = __logf(gsum);

    if (valid) {
        const size_t base = (size_t)r * M_ + t * 8;
        float4 w0, w1, l0, l1;
        w0.x = e[0] * inv; w0.y = e[1] * inv; w0.z = e[2] * inv; w0.w = e[3] * inv;
        w1.x = e[4] * inv; w1.y = e[5] * inv; w1.z = e[6] * inv; w1.w = e[7] * inv;
        l0.x = s[0] - gmax - lg; l0.y = s[1] - gmax - lg;
        l0.z = s[2] - gmax - lg; l0.w = s[3] - gmax - lg;
        l1.x = s[4] - gmax - lg; l1.y = s[5] - gmax - lg;
        l1.z = s[6] - gmax - lg; l1.w = s[7] - gmax - lg;
        *reinterpret_cast<float4*>(w + base)     = w0;
        *reinterpret_cast<float4*>(w + base + 4) = w1;
        if (write_hat) {
            *reinterpret_cast<float4*>(w_hat + base)     = w0;
            *reinterpret_cast<float4*>(w_hat + base + 4) = w1;
        }
        *reinterpret_cast<float4*>(logw + base)     = l0;
        *reinterpret_cast<float4*>(logw + base + 4) = l1;
        if (wb) {
            bf16x8 bv;
            bv[0] = f2bf(w0.x); bv[1] = f2bf(w0.y); bv[2] = f2bf(w0.z); bv[3] = f2bf(w0.w);
            bv[4] = f2bf(w1.x); bv[5] = f2bf(w1.y); bv[6] = f2bf(w1.z); bv[7] = f2bf(w1.w);
            *reinterpret_cast<bf16x8*>(wb + (size_t)r * MP_ + t * 8) = bv;
        }
    } else if (wb) {
        bf16x8 zv = {0, 0, 0, 0, 0, 0, 0, 0};
        *reinterpret_cast<bf16x8*>(wb + (size_t)r * MP_ + t * 8) = zv;
    }
}

__global__ __launch_bounds__(256) void copy_kernel(const float* __restrict__ src,
                                                   float* __restrict__ dst, int n4) {
    int i = blockIdx.x * 256 + threadIdx.x;
    int stride = gridDim.x * 256;
    for (; i < n4; i += stride)
        reinterpret_cast<float4*>(dst)[i] = reinterpret_cast<const float4*>(src)[i];
}

// ---------------------------------------------------------------------------
extern "C" void kernel_launch(void* const* d_in, const int* in_sizes, int n_in,
                              void* d_out, int out_size, void* d_ws, size_t ws_size,
                              hipStream_t stream) {
    const float* z      = (const float*)d_in[0];
    const int*   cls    = (const int*)d_in[1];
    const float* memory = (const float*)d_in[2];

    float* out   = (float*)d_out;
    float* z_hat = out;                                  //  8,388,608 fp32
    float* w_hat = z_hat + (size_t)N_ * C_ * HW_;        // 32,768,000
    float* w     = w_hat + (size_t)N_ * HW_ * M_;        // 32,768,000
    float* logw  = w     + (size_t)N_ * HW_ * M_;        // 32,768,000

    const size_t mcm_sh = (size_t)KCLS * C_ * MP_;       // bf16 elems
    const size_t mmc_sh = mcm_sh;
    const size_t zTb_sh = (size_t)N_ * HW_ * C_;
    const size_t wb_sh  = (size_t)N_ * HW_ * MP_;
    const size_t m2_fl  = (size_t)KCLS * MP_;
    const size_t need_base = (mcm_sh + mmc_sh + zTb_sh) * 2 + m2_fl * 4 + 256;
    const size_t need_full = need_base + wb_sh * 2;

    short *mcm, *mmc, *zTb, *wb = nullptr;
    float* m2;
    int* perm;
    int write_hat;
    if (ws_size >= need_base) {
        char* p = (char*)d_ws;
        mcm  = (short*)p;         p += mcm_sh * 2;
        mmc  = (short*)p;         p += mmc_sh * 2;
        m2   = (float*)p;         p += m2_fl * 4;
        perm = (int*)p;           p += 256;
        zTb  = (short*)p;         p += zTb_sh * 2;
        if (ws_size >= need_full) wb = (short*)p;
        write_hat = 1;
    } else {
        // fallback: stage mcm+mmc+m2+perm in the w_hat slot, zTb in z_hat slot,
        // copy w -> w_hat at the end.
        char* p = (char*)w_hat;
        mcm  = (short*)p;         p += mcm_sh * 2;
        mmc  = (short*)p;         p += mmc_sh * 2;
        m2   = (float*)p;         p += m2_fl * 4;
        perm = (int*)p;
        zTb  = (short*)z_hat;
        write_hat = 0;
    }
    // bf16 sim aliased into the logw slot (block-private row regions)
    short* simb = (short*)logw;

    hipMemsetAsync(m2, 0, m2_fl * sizeof(float), stream);
    prep_kernel<<<2561, 256, 0, stream>>>(memory, z, cls, mcm, mmc, zTb, m2, perm);
    gemm_nt<0><<<dim3(16, 2, N_), 256, 0, stream>>>(zTb, mmc, nullptr, cls, perm, m2, logw);
    softmax_kernel<<<N_ * HW_, 256, 0, stream>>>(simb, w_hat, w, logw, wb, write_hat);
    if (wb)
        gemm_nt<2><<<dim3(2, 4, N_), 256, 0, stream>>>(mcm, wb, nullptr, cls, perm, m2, z_hat);
    else
        gemm_nt<1><<<dim3(2, 4, N_), 256, 0, stream>>>(mcm, nullptr, w, cls, perm, m2, z_hat);
    if (!write_hat)
        copy_kernel<<<2048, 256, 0, stream>>>(w, w_hat, (N_ * HW_ * M_) / 4);
}